// Round 15
// baseline (2281.806 us; speedup 1.0000x reference)
//
#include <hip/hip_runtime.h>
#include <hip/hip_bf16.h>
#include <math.h>

#define BB 32
#define NMAX 2048
#define HD 256
#define KNN 6
#define OUTD 128
#define NCH 8

typedef __hip_bfloat16 bf16;

// XCD-locality mapping: block g, wave w -> (batch, node).
__device__ __forceinline__ void xcd_map(int g, int wave, int n, int& b, int& d){
  int P=(n+3)>>2;
  int r=g&7, q=g>>3;
  b=r+8*(q/P);
  d=(q%P)*4+wave;
}

// ---------------- dtype detect ----------------
__global__ void k_detect(const void* __restrict__ x, int* __restrict__ flag){
  __shared__ int cnt_s;
  if (threadIdx.x==0) cnt_s=0;
  __syncthreads();
  const unsigned short* u=(const unsigned short*)x;
  int c=0;
  for (int i=threadIdx.x;i<4096;i+=256){
    int e=(u[i]>>7)&0xFF;
    if (e>=0xC0) c++;
  }
  atomicAdd(&cnt_s,c);
  __syncthreads();
  if (threadIdx.x==0) flag[0]=(cnt_s>32)?1:0;
}

__device__ __forceinline__ float loadx(const void* x, int fl, size_t idx){
  if (fl) return ((const float*)x)[idx];
  unsigned short u=((const unsigned short*)x)[idx];
  return __uint_as_float(((unsigned)u)<<16);
}
__device__ __forceinline__ float4 loadx4(const void* x, int fl, size_t idx){
  if (fl) return *(const float4*)((const float*)x+idx);
  float4 r;
  r.x=loadx(x,0,idx); r.y=loadx(x,0,idx+1); r.z=loadx(x,0,idx+2); r.w=loadx(x,0,idx+3);
  return r;
}

__global__ void k_cvtpos(const void* __restrict__ pos, const int* __restrict__ flag,
                         float* __restrict__ posF){
  int t=blockIdx.x*256+threadIdx.x;
  if (t>=BB*NMAX*3) return;
  posF[t]=loadx(pos,flag[0],t);
}
struct WTab { const void* src[25]; int cnt[25]; int dst[25]; };
__global__ void k_cvtw(WTab tab, const int* __restrict__ flag, float* __restrict__ wsW){
  int seg=blockIdx.y;
  int t=blockIdx.x*256+threadIdx.x;
  if (t>=tab.cnt[seg]) return;
  wsW[tab.dst[seg]+t]=loadx(tab.src[seg],flag[0],t);
}

__global__ void k_initcum(int* __restrict__ cum){
  int t=blockIdx.x*256+threadIdx.x;
  if (t<BB*NMAX) cum[t]=t%NMAX;
}
__global__ void k_gatherpos(const float* __restrict__ posF, const int* __restrict__ cum,
                            float* __restrict__ posf, int n){
  int t=blockIdx.x*256+threadIdx.x;
  if (t>=BB*n*3) return;
  int c=t%3, i=(t/3)%n, b=t/(3*n);
  posf[t]=posF[((size_t)b*NMAX+cum[b*NMAX+i])*3+c];
}

// ---------------- knn part: f32 prune + exact f64 verify ----------------
__global__ void k_knn_part(const float* __restrict__ posf, double* __restrict__ dcand,
                           int* __restrict__ icand, int n){
  int b=blockIdx.z, ch=blockIdx.y;
  int i=blockIdx.x*256+threadIdx.x;
  const float* pp=posf+(size_t)b*n*3;
  int cs=(n+NCH-1)/NCH;
  int jlo=ch*cs, jhi=jlo+cs; if (jhi>n) jhi=n;
  float pxf=0.f,pyf=0.f,pzf=0.f;
  double px=0.0,py=0.0,pz=0.0;
  if (i<n){
    pxf=pp[i*3]; pyf=pp[i*3+1]; pzf=pp[i*3+2];
    px=(double)pxf; py=(double)pyf; pz=(double)pzf;
  }
  double bd0=INFINITY,bd1=INFINITY,bd2=INFINITY,bd3=INFINITY,bd4=INFINITY,bd5=INFINITY;
  float bd5f=INFINITY;
  int   bi0=0x7fffffff,bi1=0x7fffffff,bi2=0x7fffffff,bi3=0x7fffffff,bi4=0x7fffffff,bi5=0x7fffffff;
  __shared__ float sx[256],sy[256],sz[256];
  for (int base=jlo;base<jhi;base+=256){
    int j=base+threadIdx.x;
    if (j<jhi){ sx[threadIdx.x]=pp[j*3]; sy[threadIdx.x]=pp[j*3+1]; sz[threadIdx.x]=pp[j*3+2]; }
    __syncthreads();
    int lim=jhi-base; if (lim>256) lim=256;
    if (i<n){
      for (int t=0;t<lim;t++){
        float dxf=pxf-sx[t], dyf=pyf-sy[t], dzf=pzf-sz[t];
        float d2f=fmaf(dxf,dxf,fmaf(dyf,dyf,dzf*dzf));
        if (d2f<=bd5f){
          double dx=__dsub_rn(px,(double)sx[t]);
          double dy=__dsub_rn(py,(double)sy[t]);
          double dz=__dsub_rn(pz,(double)sz[t]);
          double d2=__dadd_rn(__dadd_rn(__dmul_rn(dx,dx),__dmul_rn(dy,dy)),__dmul_rn(dz,dz));
          if (d2<bd5){
            int id=base+t;
            if (d2<bd4){ bd5=bd4; bi5=bi4;
              if (d2<bd3){ bd4=bd3; bi4=bi3;
                if (d2<bd2){ bd3=bd2; bi3=bi2;
                  if (d2<bd1){ bd2=bd1; bi2=bi1;
                    if (d2<bd0){ bd1=bd0; bi1=bi0; bd0=d2; bi0=id; }
                    else { bd1=d2; bi1=id; }
                  } else { bd2=d2; bi2=id; }
                } else { bd3=d2; bi3=id; }
              } else { bd4=d2; bi4=id; }
            } else { bd5=d2; bi5=id; }
            bd5f=(float)(bd5*1.00001);
          }
        }
      }
    }
    __syncthreads();
  }
  if (i<n){
    size_t o=(((size_t)b*NCH+ch)*n+i)*KNN;
    dcand[o+0]=bd0; dcand[o+1]=bd1; dcand[o+2]=bd2; dcand[o+3]=bd3; dcand[o+4]=bd4; dcand[o+5]=bd5;
    icand[o+0]=bi0; icand[o+1]=bi1; icand[o+2]=bi2; icand[o+3]=bi3; icand[o+4]=bi4; icand[o+5]=bi5;
  }
}

// ---------------- knn merge (+ zero cnt/cur for the CSR pass) ----------------
__global__ void k_knn_merge(const double* __restrict__ dcand, const int* __restrict__ icand,
                            int* __restrict__ nbr, int* __restrict__ cnt, int* __restrict__ cur,
                            int n){
  int t=blockIdx.x*256+threadIdx.x;
  if (t>=BB*n) return;
  cnt[t]=0; cur[t]=0;
  int b=t/n, i=t-b*n;
  double cd[NCH*KNN]; int ci[NCH*KNN];
  #pragma unroll
  for (int ch=0;ch<NCH;ch++){
    size_t o=(((size_t)b*NCH+ch)*n+i)*KNN;
    #pragma unroll
    for (int k=0;k<KNN;k++){ cd[ch*KNN+k]=dcand[o+k]; ci[ch*KNN+k]=icand[o+k]; }
  }
  int* out=nbr+(size_t)t*KNN;
  #pragma unroll
  for (int k=0;k<KNN;k++){
    int best=0;
    for (int q=1;q<NCH*KNN;q++){
      bool lt=(cd[q]<cd[best])||(cd[q]==cd[best]&&ci[q]<ci[best]);
      if (lt) best=q;
    }
    out[k]=ci[best];
    cd[best]=INFINITY; ci[best]=0x7fffffff;
  }
}

// ---------------- edge weights + validity + CSR count ----------------
__global__ void k_edge(const float* __restrict__ posf, const int* __restrict__ nbr,
                       float* __restrict__ w1, float* __restrict__ w2,
                       unsigned char* __restrict__ val2, int* __restrict__ cnt,
                       const float* __restrict__ W1, const float* __restrict__ b1,
                       const float* __restrict__ g,  const float* __restrict__ be,
                       const float* __restrict__ m,  const float* __restrict__ v,
                       const float* __restrict__ W2, const float* __restrict__ b2p,
                       int n){
  int t=blockIdx.x*256+threadIdx.x;
  if (t>=BB*n*KNN) return;
  int k=t%KNN; int c=(t/KNN)%n; int b=t/(KNN*n);
  const int* nb=nbr+(size_t)b*n*KNN;
  int j=nb[c*KNN+k];
  atomicAdd(&cnt[b*n+j],1);
  bool dup=false;
  #pragma unroll
  for (int kk=0;kk<KNN;kk++) dup=dup||(nb[j*KNN+kk]==c);
  const float* pp=posf+(size_t)b*n*3;
  double dx=__dsub_rn((double)pp[c*3+0],(double)pp[j*3+0]);
  double dy=__dsub_rn((double)pp[c*3+1],(double)pp[j*3+1]);
  double dz=__dsub_rn((double)pp[c*3+2],(double)pp[j*3+2]);
  double d2=__dadd_rn(__dadd_rn(__dmul_rn(dx,dx),__dmul_rn(dy,dy)),__dmul_rn(dz,dz));
  float dd=(float)sqrt(d2);
  float wv;
  if (j==c) wv=1.0f;
  else {
    float acc=b2p[0];
    for (int q=0;q<32;q++){
      float tt=dd*W1[q]+b1[q];
      float r=1.0f/sqrtf(v[q]+1e-5f);
      tt=(tt-m[q])*r*g[q]+be[q];
      tt=fmaxf(tt,0.f);
      acc=fmaf(tt,W2[q],acc);
    }
    wv=fmaxf(acc,0.f);
  }
  w1[t]=wv;
  w2[t]=dup?0.f:wv;
  val2[t]=dup?0:1;
}

// ---------------- reverse CSR ----------------
__global__ void k_csr_scan(const int* __restrict__ cnt, int* __restrict__ offs, int n){
  int b=blockIdx.x, t=threadIdx.x;
  int L=(n+255)/256;
  __shared__ int ssum[256];
  int lo=t*L, hi=lo+L; if (hi>n) hi=n; if (lo>n) lo=n;
  int s=0;
  for (int i=lo;i<hi;i++) s+=cnt[b*n+i];
  ssum[t]=s;
  __syncthreads();
  if (t==0){
    int run=0;
    for (int q=0;q<256;q++){ int vv=ssum[q]; ssum[q]=run; run+=vv; }
  }
  __syncthreads();
  int run=ssum[t];
  for (int i=lo;i<hi;i++){ offs[b*(n+1)+i]=run; run+=cnt[b*n+i]; }
  if (lo<n && hi==n) offs[b*(n+1)+n]=run;
}
__global__ void k_csr_fill(const int* __restrict__ nbr, const int* __restrict__ offs,
                           int* __restrict__ cur, int* __restrict__ rev, int n){
  int t=blockIdx.x*256+threadIdx.x;
  if (t>=BB*n*KNN) return;
  int b=t/(n*KNN); int rem=t-b*n*KNN;
  int d=nbr[t];
  int slot=offs[b*(n+1)+d]+atomicAdd(&cur[b*n+d],1);
  if (slot<0) slot=0;
  if (slot>=n*KNN) slot=n*KNN-1;
  rev[(size_t)b*n*KNN+slot]=rem;
}
__global__ void k_sortdeg(int* __restrict__ rev, const int* __restrict__ offs,
                          const float* __restrict__ w1, const float* __restrict__ w2,
                          float* __restrict__ dis, int n){
  int t=blockIdx.x*256+threadIdx.x;
  if (t>=BB*n) return;
  int b=t/n, d=t-b*n;
  size_t base=(size_t)b*n*KNN;
  int lo=offs[b*(n+1)+d], hi=offs[b*(n+1)+d+1];
  for (int a2=lo+1;a2<hi;a2++){
    int vv=rev[base+a2]; int p=a2;
    while (p>lo && rev[base+p-1]>vv){ rev[base+p]=rev[base+p-1]; p--; }
    rev[base+p]=vv;
  }
  float s=0.f;
  #pragma unroll
  for (int k=0;k<KNN;k++) s+=w1[(size_t)t*KNN+k];
  for (int sl=lo;sl<hi;sl++) s+=w2[base+rev[base+sl]];
  dis[t]=1.0f/sqrtf(fmaxf(s,1e-12f));
}

// ---------------- weighted nbr sum (float4, XCD-local) ----------------
template<int MODE,int RAW>
__global__ void k_nbrsum(const float* __restrict__ Hin, const float* __restrict__ w1,
                         const float* __restrict__ w2, const int* __restrict__ nbr,
                         const int* __restrict__ rev, const int* __restrict__ offs,
                         const float* __restrict__ dis, const void* __restrict__ xraw,
                         const int* __restrict__ flag,
                         const int* __restrict__ cum, float* __restrict__ outp, int n){
  int b,d;
  xcd_map(blockIdx.x,threadIdx.x>>6,n,b,d);
  int lane=threadIdx.x&63;
  if (d>=n) return;
  int wid=b*n+d;
  int fl=flag[0];
  const float* Hb=Hin+(size_t)b*n*HD;
  float4 a=make_float4(0.f,0.f,0.f,0.f);
  float dd=(MODE==0)?dis[wid]:0.f;
  int c4=lane*4;
  #pragma unroll
  for (int k=0;k<KNN;k++){
    int sN=nbr[(size_t)wid*KNN+k];
    float wv=w1[(size_t)wid*KNN+k];
    float nm=(MODE==0)?dis[b*n+sN]*wv*dd:wv;
    float4 r = RAW ? loadx4(xraw,fl,((size_t)b*n+sN)*HD+c4)
                   : *(const float4*)(Hb+(size_t)sN*HD+c4);
    a.x=fmaf(nm,r.x,a.x); a.y=fmaf(nm,r.y,a.y); a.z=fmaf(nm,r.z,a.z); a.w=fmaf(nm,r.w,a.w);
  }
  size_t rbase=(size_t)b*n*KNN;
  int lo=offs[b*(n+1)+d], hi=offs[b*(n+1)+d+1];
  for (int sl=lo;sl<hi;sl++){
    int e=rev[rbase+sl];
    int sN=e/KNN;
    float wv=w2[rbase+e];
    float nm=(MODE==0)?dis[b*n+sN]*wv*dd:wv;
    float4 r = RAW ? loadx4(xraw,fl,((size_t)b*n+sN)*HD+c4)
                   : *(const float4*)(Hb+(size_t)sN*HD+c4);
    a.x=fmaf(nm,r.x,a.x); a.y=fmaf(nm,r.y,a.y); a.z=fmaf(nm,r.z,a.z); a.w=fmaf(nm,r.w,a.w);
  }
  if (MODE==0){
    float4 xr=loadx4(xraw,fl,((size_t)b*NMAX+cum[b*NMAX+d])*HD+c4);
    a.x=0.8f*a.x+0.2f*xr.x; a.y=0.8f*a.y+0.2f*xr.y;
    a.z=0.8f*a.z+0.2f*xr.z; a.w=0.8f*a.w+0.2f*xr.w;
  }
  *(float4*)(outp+(size_t)wid*HD+c4)=a;
}

// ---------------- unified panel GEMM, 8x8 tile, reg-prefetch pipeline ----------------
__global__ __launch_bounds__(256,4)
void k_mm(const float* __restrict__ A1, const float* __restrict__ B1,
          const float* __restrict__ A2, const float* __restrict__ B2,
          const float* __restrict__ bias, int relu,
          float* __restrict__ Cout, int M){
  __shared__ __align__(16) float As[16][68];
  __shared__ __align__(16) float Bs[16][260];
  int tid=threadIdx.x, bm=blockIdx.x;
  int tr=tid>>5, tc=tid&31;
  float acc[8][8];
  #pragma unroll
  for (int i=0;i<8;i++){
    #pragma unroll
    for (int j=0;j<8;j++) acc[i][j]=0.f;
  }
  int l=tid*4;
  int ar=l>>4, ak=l&15;
  int arow=bm*64+ar;
  int brow[4], bcol[4];
  #pragma unroll
  for (int c=0;c<4;c++){ int idx=c*256+tid; brow[c]=idx>>6; bcol[c]=(idx&63)*4; }
  int KT = A2 ? 512 : 256;
  float4 a4; float4 b4[4];
  a4 = (arow<M)? *(const float4*)(A1+(size_t)arow*HD+ak) : make_float4(0.f,0.f,0.f,0.f);
  #pragma unroll
  for (int c=0;c<4;c++) b4[c]=*(const float4*)(B1+(size_t)brow[c]*HD+bcol[c]);
  for (int k0=0;k0<KT;k0+=16){
    As[ak][ar]=a4.x; As[ak+1][ar]=a4.y; As[ak+2][ar]=a4.z; As[ak+3][ar]=a4.w;
    #pragma unroll
    for (int c=0;c<4;c++) *(float4*)&Bs[brow[c]][bcol[c]]=b4[c];
    __syncthreads();
    int k1=k0+16;
    if (k1<KT){                 // issue next tile's loads; latency hides under FMAs
      const float* Asrc=(k1<HD)?A1:A2;
      const float* Bsrc=(k1<HD)?B1:B2;
      int kc=k1&(HD-1);
      a4 = (arow<M)? *(const float4*)(Asrc+(size_t)arow*HD+kc+ak) : make_float4(0.f,0.f,0.f,0.f);
      #pragma unroll
      for (int c=0;c<4;c++) b4[c]=*(const float4*)(Bsrc+(size_t)(kc+brow[c])*HD+bcol[c]);
    }
    #pragma unroll
    for (int kk=0;kk<16;kk++){
      float af[8], bf[8];
      *(float4*)&af[0]=*(const float4*)&As[kk][tr*8];
      *(float4*)&af[4]=*(const float4*)&As[kk][tr*8+4];
      *(float4*)&bf[0]=*(const float4*)&Bs[kk][tc*8];
      *(float4*)&bf[4]=*(const float4*)&Bs[kk][tc*8+4];
      #pragma unroll
      for (int i=0;i<8;i++){
        #pragma unroll
        for (int j=0;j<8;j++) acc[i][j]=fmaf(af[i],bf[j],acc[i][j]);
      }
    }
    __syncthreads();
  }
  #pragma unroll
  for (int i=0;i<8;i++){
    int grow=bm*64+tr*8+i;
    if (grow>=M) continue;
    #pragma unroll
    for (int j=0;j<8;j++){
      int gcol=tc*8+j;
      float v=acc[i][j];
      if (bias) v+=bias[gcol];
      if (relu) v=fmaxf(v,0.f);
      Cout[(size_t)grow*HD+gcol]=v;
    }
  }
}

// ---------------- va = rowdot(Wlin, wa); va[256] = blin . wa ----------------
__global__ void k_va(const float* __restrict__ Wlin, const float* __restrict__ wa,
                     const float* __restrict__ blin, float* __restrict__ va){
  int i=threadIdx.x;
  float acc=0.f;
  for (int j=0;j<HD;j++) acc=fmaf(Wlin[(size_t)i*HD+j],wa[j],acc);
  va[i]=acc;
  if (i==0){
    float c=0.f;
    for (int j=0;j<HD;j++) c=fmaf(blin[j],wa[j],c);
    va[256]=c;
  }
}

// ---------------- fused: pb, qd (XCD-local) ----------------
__global__ void k_qd(const float* __restrict__ T, const float* __restrict__ wb,
                     const float* __restrict__ va, const int* __restrict__ nbr,
                     const int* __restrict__ rev, const int* __restrict__ offs,
                     const unsigned char* __restrict__ val2,
                     float* __restrict__ pb, float* __restrict__ qd, int n){
  int b,d;
  xcd_map(blockIdx.x,threadIdx.x>>6,n,b,d);
  int lane=threadIdx.x&63;
  if (d>=n) return;
  int wid=b*n+d;
  int c4=lane*4;
  float4 r1=*(const float4*)(T+(size_t)wid*HD+c4);
  float4 wb4=*(const float4*)(wb+c4);
  float p=r1.x*wb4.x+r1.y*wb4.y+r1.z*wb4.z+r1.w*wb4.w;
  const float* Tb=T+(size_t)b*n*HD;
  float4 m4=make_float4(-INFINITY,-INFINITY,-INFINITY,-INFINITY);
  #pragma unroll
  for (int k=0;k<KNN;k++){
    int sN=nbr[(size_t)wid*KNN+k];
    float4 r=*(const float4*)(Tb+(size_t)sN*HD+c4);
    m4.x=fmaxf(m4.x,r.x); m4.y=fmaxf(m4.y,r.y); m4.z=fmaxf(m4.z,r.z); m4.w=fmaxf(m4.w,r.w);
  }
  size_t rbase=(size_t)b*n*KNN;
  int lo=offs[b*(n+1)+d], hi=offs[b*(n+1)+d+1];
  for (int sl=lo;sl<hi;sl++){
    int e=rev[rbase+sl];
    if (!val2[rbase+e]) continue;
    int sN=e/KNN;
    float4 r=*(const float4*)(Tb+(size_t)sN*HD+c4);
    m4.x=fmaxf(m4.x,r.x); m4.y=fmaxf(m4.y,r.y); m4.z=fmaxf(m4.z,r.z); m4.w=fmaxf(m4.w,r.w);
  }
  float4 va4=*(const float4*)(va+c4);
  float q=va4.x*m4.x+va4.y*m4.y+va4.z*m4.z+va4.w*m4.w;
  #pragma unroll
  for (int o=32;o>0;o>>=1){ p+=__shfl_xor(p,o); q+=__shfl_xor(q,o); }
  if (lane==0){ pb[wid]=p; qd[wid]=q+va[256]; }
}

// ---------------- attention softmax + xn + fused LEConv dots (XCD-local) ----------------
__global__ void k_attxn(const float* __restrict__ Hin, const float* __restrict__ pb,
                        const float* __restrict__ qd, const int* __restrict__ nbr,
                        const int* __restrict__ rev, const int* __restrict__ offs,
                        const unsigned char* __restrict__ val2, const float* __restrict__ abatt,
                        const float* __restrict__ lW1, const float* __restrict__ lb1,
                        const float* __restrict__ lW2, const float* __restrict__ lW3,
                        const float* __restrict__ lb3,
                        float* __restrict__ av, float* __restrict__ bbv, float* __restrict__ l3v,
                        float* __restrict__ Tout, int n){
  int b,d;
  xcd_map(blockIdx.x,threadIdx.x>>6,n,b,d);
  int lane=threadIdx.x&63;
  if (d>=n) return;
  int wid=b*n+d;
  float batt=abatt[0];
  float qs=qd[wid];
  const float* Hb=Hin+(size_t)b*n*HD;
  int c4=lane*4;
  size_t rbase=(size_t)b*n*KNN;
  int lo=offs[b*(n+1)+d], hi=offs[b*(n+1)+d+1];
  float smax=-INFINITY;
  #pragma unroll
  for (int k=0;k<KNN;k++){
    int sN=nbr[(size_t)wid*KNN+k];
    float sc=qs+pb[b*n+sN]+batt;
    sc=sc>=0.f?sc:0.2f*sc;
    smax=fmaxf(smax,sc);
  }
  for (int sl=lo;sl<hi;sl++){
    int e=rev[rbase+sl];
    if (!val2[rbase+e]) continue;
    int sN=e/KNN;
    float sc=qs+pb[b*n+sN]+batt;
    sc=sc>=0.f?sc:0.2f*sc;
    smax=fmaxf(smax,sc);
  }
  float es=0.f;
  float4 a=make_float4(0.f,0.f,0.f,0.f);
  #pragma unroll
  for (int k=0;k<KNN;k++){
    int sN=nbr[(size_t)wid*KNN+k];
    float sc=qs+pb[b*n+sN]+batt;
    sc=sc>=0.f?sc:0.2f*sc;
    float e2=expf(sc-smax);
    es+=e2;
    float4 r=*(const float4*)(Hb+(size_t)sN*HD+c4);
    a.x=fmaf(e2,r.x,a.x); a.y=fmaf(e2,r.y,a.y); a.z=fmaf(e2,r.z,a.z); a.w=fmaf(e2,r.w,a.w);
  }
  for (int sl=lo;sl<hi;sl++){
    int e=rev[rbase+sl];
    if (!val2[rbase+e]) continue;
    int sN=e/KNN;
    float sc=qs+pb[b*n+sN]+batt;
    sc=sc>=0.f?sc:0.2f*sc;
    float e2=expf(sc-smax);
    es+=e2;
    float4 r=*(const float4*)(Hb+(size_t)sN*HD+c4);
    a.x=fmaf(e2,r.x,a.x); a.y=fmaf(e2,r.y,a.y); a.z=fmaf(e2,r.z,a.z); a.w=fmaf(e2,r.w,a.w);
  }
  float inv=1.f/es;
  a.x*=inv; a.y*=inv; a.z*=inv; a.w*=inv;
  *(float4*)(Tout+(size_t)wid*HD+c4)=a;
  float4 w1v=*(const float4*)(lW1+c4);
  float4 w2v=*(const float4*)(lW2+c4);
  float4 w3v=*(const float4*)(lW3+c4);
  float s1=a.x*w1v.x+a.y*w1v.y+a.z*w1v.z+a.w*w1v.w;
  float s2=a.x*w2v.x+a.y*w2v.y+a.z*w2v.z+a.w*w2v.w;
  float s3=a.x*w3v.x+a.y*w3v.y+a.z*w3v.z+a.w*w3v.w;
  #pragma unroll
  for (int o=32;o>0;o>>=1){ s1+=__shfl_xor(s1,o); s2+=__shfl_xor(s2,o); s3+=__shfl_xor(s3,o); }
  if (lane==0){ av[wid]=s1+lb1[0]; bbv[wid]=s2; l3v[wid]=s3+lb3[0]; }
}

__global__ void k_fit(const float* __restrict__ av, const float* __restrict__ bbv,
                      const float* __restrict__ l3v, const int* __restrict__ nbr,
                      const int* __restrict__ rev, const int* __restrict__ offs,
                      const unsigned char* __restrict__ val2, float* __restrict__ fit, int n){
  int t=blockIdx.x*256+threadIdx.x;
  if (t>=BB*n) return;
  int b=t/n, d=t-b*n;
  size_t rbase=(size_t)b*n*KNN;
  float ms=0.f; int cv=KNN;
  #pragma unroll
  for (int k=0;k<KNN;k++) ms+=av[b*n+nbr[(size_t)t*KNN+k]];
  int lo=offs[b*(n+1)+d], hi=offs[b*(n+1)+d+1];
  for (int sl=lo;sl<hi;sl++){
    int e=rev[rbase+sl];
    if (val2[rbase+e]){ ms+=av[b*n+e/KNN]; cv++; }
  }
  float z=ms-(float)cv*bbv[t]+l3v[t];
  fit[t]=1.f/(1.f+expf(-z));
}

// ---------------- top-k by rank-counting, LDS-staged ----------------
__global__ void k_rank(const float* __restrict__ fit, float* __restrict__ svl,
                       int* __restrict__ sid, int n, int kp){
  __shared__ float sf[2048];
  int b=blockIdx.y;
  int i=blockIdx.x*256+threadIdx.x;
  const float* fb=fit+(size_t)b*n;
  for (int j=threadIdx.x;j<n;j+=256) sf[j]=fb[j];
  __syncthreads();
  if (i>=n) return;
  float fi=sf[i];
  int rank=0;
  for (int j=0;j<n;j++){
    float fj=sf[j];
    if (fj>fi || (fj==fi && j<i)) rank++;
  }
  if (rank<kp){ svl[b*NMAX+rank]=fi; sid[b*NMAX+rank]=i; }
}

// ---------------- pool gather (float4) ----------------
__global__ void k_pool(const float* __restrict__ T, const float* __restrict__ svl,
                       const int* __restrict__ sid, const int* __restrict__ cumA,
                       int* __restrict__ cumB, float* __restrict__ Hout, int n, int kp){
  int wid=blockIdx.x*4+(threadIdx.x>>6);
  int lane=threadIdx.x&63;
  if (wid>=BB*kp) return;
  int b=wid/kp, j=wid-b*kp;
  int srcn=sid[b*NMAX+j];
  if (srcn<0) srcn=0;
  if (srcn>=n) srcn=n-1;
  float vv=svl[b*NMAX+j];
  int c4=lane*4;
  float4 r=*(const float4*)(T+((size_t)b*n+srcn)*HD+c4);
  r.x*=vv; r.y*=vv; r.z*=vv; r.w*=vv;
  *(float4*)(Hout+((size_t)b*kp+j)*HD+c4)=r;
  if (lane==0) cumB[b*NMAX+j]=cumA[b*NMAX+srcn];
}

// ---------------- readout: [mean | max], 4-wave parallel ----------------
__global__ void k_readout(const float* __restrict__ Hb, float* __restrict__ ro, int n){
  __shared__ float ss[4][256], sm[4][256];
  int b=blockIdx.x, tid=threadIdx.x;
  int wv=tid>>6, lane=tid&63;
  int c4=lane*4;
  float4 s=make_float4(0.f,0.f,0.f,0.f);
  float4 m=make_float4(-INFINITY,-INFINITY,-INFINITY,-INFINITY);
  for (int i=wv;i<n;i+=4){
    float4 v=*(const float4*)(Hb+((size_t)b*n+i)*HD+c4);
    s.x+=v.x; s.y+=v.y; s.z+=v.z; s.w+=v.w;
    m.x=fmaxf(m.x,v.x); m.y=fmaxf(m.y,v.y); m.z=fmaxf(m.z,v.z); m.w=fmaxf(m.w,v.w);
  }
  *(float4*)&ss[wv][c4]=s;
  *(float4*)&sm[wv][c4]=m;
  __syncthreads();
  int h=tid;   // channel
  float acc=ss[0][h]+ss[1][h]+ss[2][h]+ss[3][h];
  float mx=fmaxf(fmaxf(sm[0][h],sm[1][h]),fmaxf(sm[2][h],sm[3][h]));
  ro[b*512+h]=acc/(float)n;
  ro[b*512+256+h]=mx;
}

// ---------------- final ----------------
__global__ void k_final(const float* __restrict__ Hb, const float* __restrict__ gW,
                        const float* __restrict__ gb, const float* __restrict__ nW,
                        const float* __restrict__ nbias, const float* __restrict__ ro0,
                        const float* __restrict__ ro1, float* __restrict__ outp, int n){
  int b=blockIdx.x, tid=threadIdx.x;
  int wv=tid>>6, lane=tid&63;
  __shared__ float gate[64];
  for (int i=wv;i<n;i+=4){
    const float* r=Hb+((size_t)b*n+i)*HD;
    float p=0.f;
    for (int h=lane;h<HD;h+=64) p=fmaf(r[h],gW[h],p);
    #pragma unroll
    for (int o=32;o>0;o>>=1) p+=__shfl_xor(p,o);
    if (lane==0) gate[i]=p+gb[0];
  }
  __syncthreads();
  if (tid==0){
    float mx=-INFINITY;
    for (int i=0;i<n;i++) mx=fmaxf(mx,gate[i]);
    float sm=0.f;
    for (int i=0;i<n;i++){ gate[i]=expf(gate[i]-mx); sm+=gate[i]; }
    float inv=1.f/sm;
    for (int i=0;i<n;i++) gate[i]*=inv;
  }
  __syncthreads();
  if (tid<OUTD){
    float acc=0.f;
    for (int i=0;i<n;i++){
      const float* r=Hb+((size_t)b*n+i)*HD;
      float dot=0.f;
      for (int h=0;h<HD;h++) dot=fmaf(r[h],nW[(size_t)h*OUTD+tid],dot);
      acc=fmaf(gate[i],dot+nbias[tid],acc);
    }
    outp[(size_t)b*1152+tid]=acc;
  }
  for (int q=tid;q<512;q+=256){
    outp[(size_t)b*1152+128+q]=ro1[b*512+q];
    outp[(size_t)b*1152+640+q]=ro0[b*512+q];
  }
}

// =======================================================================
extern "C" void kernel_launch(void* const* d_in, const int* in_sizes, int n_in,
                              void* d_out, int out_size, void* d_ws, size_t ws_size,
                              hipStream_t stream){
  if (n_in<27) return;
  if (in_sizes[0]!=BB*NMAX*HD || in_sizes[1]!=BB*NMAX*3) return;
  float* outp=(float*)d_out;
  (void)out_size;

  char* p=(char*)d_ws;
  auto carve=[&](size_t bytes)->char*{ char* r=p; p+=((bytes+255)/256)*256; return r; };
  float* posF=(float*)carve((size_t)BB*NMAX*3*4);
  float* posf=(float*)carve((size_t)BB*NMAX*3*4);
  float* Hbuf=(float*)carve((size_t)BB*NMAX*HD*4);
  float* Tbuf=(float*)carve((size_t)BB*NMAX*HD*4);
  static const int wcnt[25]={262144,128,128,128,128,128,128,128,4,
                             196608,768,196608,196608,768,1536,3,
                             768,3,768,768,3,256,1,32768,128};
  int woff[25]; int wtot=0;
  for (int i=0;i<25;i++){ woff[i]=wtot; wtot+=(wcnt[i]+63)&~63; }
  float* wsW=(float*)carve((size_t)wtot*4);
  int*   nbr =(int*)  carve((size_t)BB*NMAX*KNN*4);
  int*   rev =(int*)  carve((size_t)BB*NMAX*KNN*4);
  float* w1  =(float*)carve((size_t)BB*NMAX*KNN*4);
  float* w2  =(float*)carve((size_t)BB*NMAX*KNN*4);
  unsigned char* val2=(unsigned char*)carve((size_t)BB*NMAX*KNN);
  int* cnt  =(int*)carve((size_t)BB*NMAX*4);
  int* offs =(int*)carve((size_t)BB*(NMAX+1)*4);
  int* cur  =(int*)carve((size_t)BB*NMAX*4);
  float* dis=(float*)carve((size_t)BB*NMAX*4);
  float* pb =(float*)carve((size_t)BB*NMAX*4);
  float* qd =(float*)carve((size_t)BB*NMAX*4);
  float* av =(float*)carve((size_t)BB*NMAX*4);
  float* bbv=(float*)carve((size_t)BB*NMAX*4);
  float* l3v=(float*)carve((size_t)BB*NMAX*4);
  float* fit=(float*)carve((size_t)BB*NMAX*4);
  float* svl=(float*)carve((size_t)BB*NMAX*4);
  int*   sid=(int*)  carve((size_t)BB*NMAX*4);
  int* cumA =(int*)carve((size_t)BB*NMAX*4);
  int* cumB =(int*)carve((size_t)BB*NMAX*4);
  int* flag =(int*)carve(256);
  float* va =(float*)carve(272*4);
  float* ro0=(float*)carve((size_t)BB*512*4);
  float* ro1=(float*)carve((size_t)BB*512*4);
  size_t need=(size_t)(p-(char*)d_ws);
  if (ws_size<need) return;

  double* dcand=(double*)Tbuf;
  int*    icand=(int*)((char*)Tbuf + (size_t)BB*NCH*NMAX*KNN*8);

  k_detect<<<1,256,0,stream>>>(d_in[0],flag);
  k_cvtpos<<<(BB*NMAX*3+255)/256,256,0,stream>>>(d_in[1],flag,posF);
  {
    WTab tab;
    int maxc=0;
    for (int i=0;i<25;i++){ tab.src[i]=d_in[2+i]; tab.cnt[i]=wcnt[i]; tab.dst[i]=woff[i]; if (wcnt[i]>maxc) maxc=wcnt[i]; }
    k_cvtw<<<dim3((maxc+255)/256,25),256,0,stream>>>(tab,flag,wsW);
  }
  k_initcum<<<(BB*NMAX+255)/256,256,0,stream>>>(cumA);

  const int NS[4]={2048,308,77,39};
  const int KP[3]={308,77,39};

  for (int s=0;s<4;s++){
    int n=NS[s]; int M=BB*n;
    int gG=BB*((n+3)/4);
    const float* wconv =wsW+woff[0]+(size_t)s*65536;
    const float* eW1p  =wsW+woff[1]+s*32;
    const float* eb1p  =wsW+woff[2]+s*32;
    const float* gp    =wsW+woff[3]+s*32;
    const float* bep   =wsW+woff[4]+s*32;
    const float* mp    =wsW+woff[5]+s*32;
    const float* vp    =wsW+woff[6]+s*32;
    const float* W2p   =wsW+woff[7]+s*32;
    const float* b2p   =wsW+woff[8]+s;
    const float* aWrelp=wsW+woff[9]+(size_t)s*65536;
    const float* abrelp=wsW+woff[10]+s*256;
    const float* aWrootp=wsW+woff[11]+(size_t)s*65536;
    const float* aWlinp=wsW+woff[12]+(size_t)s*65536;
    const float* ablinp=wsW+woff[13]+s*256;
    const float* wap   =wsW+woff[14]+s*512;
    const float* wbp   =wsW+woff[14]+s*512+256;
    const float* abattp=wsW+woff[15]+s;
    const float* leW1p =wsW+woff[16]+s*256;
    const float* leb1p =wsW+woff[17]+s;
    const float* leW2p =wsW+woff[18]+s*256;
    const float* leW3p =wsW+woff[19]+s*256;
    const float* leb3p =wsW+woff[20]+s;

    const float* pf;
    if (s==0){
      pf=posF;
    } else {
      k_gatherpos<<<(BB*n*3+255)/256,256,0,stream>>>(posF,cumA,posf,n);
      pf=posf;
    }
    k_knn_part<<<dim3((n+255)/256,NCH,BB),256,0,stream>>>(pf,dcand,icand,n);
    k_knn_merge<<<(BB*n+255)/256,256,0,stream>>>(dcand,icand,nbr,cnt,cur,n);
    int totE=BB*n*KNN;
    k_edge<<<(totE+255)/256,256,0,stream>>>(pf,nbr,w1,w2,val2,cnt,
        eW1p,eb1p,gp,bep,mp,vp,W2p,b2p,n);
    k_csr_scan<<<BB,256,0,stream>>>(cnt,offs,n);
    k_csr_fill<<<(totE+255)/256,256,0,stream>>>(nbr,offs,cur,rev,n);
    k_sortdeg<<<(BB*n+255)/256,256,0,stream>>>(rev,offs,w1,w2,dis,n);
    if (s==1) k_readout<<<BB,256,0,stream>>>(Hbuf,ro0,n);
    if (s==2) k_readout<<<BB,256,0,stream>>>(Hbuf,ro1,n);
    if (s==0)
      k_nbrsum<0,1><<<gG,256,0,stream>>>(nullptr,w1,w2,nbr,rev,offs,dis,d_in[0],flag,cumA,Tbuf,n);
    else
      k_nbrsum<0,0><<<gG,256,0,stream>>>(Hbuf,w1,w2,nbr,rev,offs,dis,d_in[0],flag,cumA,Tbuf,n);
    k_mm<<<(M+63)/64,256,0,stream>>>(Tbuf,wconv,(const float*)nullptr,(const float*)nullptr,
                                     (const float*)nullptr,1,Hbuf,M);
    if (s<3){
      int kp=KP[s];
      k_nbrsum<1,0><<<gG,256,0,stream>>>(Hbuf,w1,w2,nbr,rev,offs,dis,d_in[0],flag,cumA,Tbuf,n);
      k_mm<<<(M+63)/64,256,0,stream>>>(Tbuf,aWrelp,Hbuf,aWrootp,abrelp,0,Tbuf,M);
      k_va<<<1,256,0,stream>>>(aWlinp,wap,ablinp,va);
      k_qd<<<gG,256,0,stream>>>(Tbuf,wbp,va,nbr,rev,offs,val2,pb,qd,n);
      k_attxn<<<gG,256,0,stream>>>(Hbuf,pb,qd,nbr,rev,offs,val2,abattp,
                                   leW1p,leb1p,leW2p,leW3p,leb3p,av,bbv,l3v,Tbuf,n);
      k_fit<<<(BB*n+255)/256,256,0,stream>>>(av,bbv,l3v,nbr,rev,offs,val2,fit,n);
      k_rank<<<dim3((n+255)/256,BB),256,0,stream>>>(fit,svl,sid,n,kp);
      k_pool<<<(BB*kp+3)/4,256,0,stream>>>(Tbuf,svl,sid,cumA,cumB,Hbuf,n,kp);
      { int* t=cumA; cumA=cumB; cumB=t; }
    }
  }
  k_final<<<BB,256,0,stream>>>(Hbuf,wsW+woff[21],wsW+woff[22],wsW+woff[23],wsW+woff[24],
                               ro0,ro1,outp,NS[3]);
}

// Round 16
// 2019.989 us; speedup vs baseline: 1.1296x; 1.1296x over previous
//
#include <hip/hip_runtime.h>
#include <hip/hip_bf16.h>
#include <math.h>

#define BB 32
#define NMAX 2048
#define HD 256
#define KNN 6
#define OUTD 128
#define NCH 8

typedef __hip_bfloat16 bf16;

// XCD-locality mapping: block g, wave w -> (batch, node).
__device__ __forceinline__ void xcd_map(int g, int wave, int n, int& b, int& d){
  int P=(n+3)>>2;
  int r=g&7, q=g>>3;
  b=r+8*(q/P);
  d=(q%P)*4+wave;
}

// ---------------- dtype detect ----------------
__global__ void k_detect(const void* __restrict__ x, int* __restrict__ flag){
  __shared__ int cnt_s;
  if (threadIdx.x==0) cnt_s=0;
  __syncthreads();
  const unsigned short* u=(const unsigned short*)x;
  int c=0;
  for (int i=threadIdx.x;i<4096;i+=256){
    int e=(u[i]>>7)&0xFF;
    if (e>=0xC0) c++;
  }
  atomicAdd(&cnt_s,c);
  __syncthreads();
  if (threadIdx.x==0) flag[0]=(cnt_s>32)?1:0;
}

__device__ __forceinline__ float loadx(const void* x, int fl, size_t idx){
  if (fl) return ((const float*)x)[idx];
  unsigned short u=((const unsigned short*)x)[idx];
  return __uint_as_float(((unsigned)u)<<16);
}
__device__ __forceinline__ float4 loadx4(const void* x, int fl, size_t idx){
  if (fl) return *(const float4*)((const float*)x+idx);
  float4 r;
  r.x=loadx(x,0,idx); r.y=loadx(x,0,idx+1); r.z=loadx(x,0,idx+2); r.w=loadx(x,0,idx+3);
  return r;
}

__global__ void k_cvtpos(const void* __restrict__ pos, const int* __restrict__ flag,
                         float* __restrict__ posF){
  int t=blockIdx.x*256+threadIdx.x;
  if (t>=BB*NMAX*3) return;
  posF[t]=loadx(pos,flag[0],t);
}
struct WTab { const void* src[25]; int cnt[25]; int dst[25]; };
__global__ void k_cvtw(WTab tab, const int* __restrict__ flag, float* __restrict__ wsW){
  int seg=blockIdx.y;
  int t=blockIdx.x*256+threadIdx.x;
  if (t>=tab.cnt[seg]) return;
  wsW[tab.dst[seg]+t]=loadx(tab.src[seg],flag[0],t);
}

__global__ void k_initcum(int* __restrict__ cum){
  int t=blockIdx.x*256+threadIdx.x;
  if (t<BB*NMAX) cum[t]=t%NMAX;
}
__global__ void k_gatherpos(const float* __restrict__ posF, const int* __restrict__ cum,
                            float* __restrict__ posf, int n){
  int t=blockIdx.x*256+threadIdx.x;
  if (t>=BB*n*3) return;
  int c=t%3, i=(t/3)%n, b=t/(3*n);
  posf[t]=posF[((size_t)b*NMAX+cum[b*NMAX+i])*3+c];
}

// ---------------- knn part: f32 prune + exact f64 verify ----------------
__global__ void k_knn_part(const float* __restrict__ posf, double* __restrict__ dcand,
                           int* __restrict__ icand, int n){
  int b=blockIdx.z, ch=blockIdx.y;
  int i=blockIdx.x*256+threadIdx.x;
  const float* pp=posf+(size_t)b*n*3;
  int cs=(n+NCH-1)/NCH;
  int jlo=ch*cs, jhi=jlo+cs; if (jhi>n) jhi=n;
  float pxf=0.f,pyf=0.f,pzf=0.f;
  double px=0.0,py=0.0,pz=0.0;
  if (i<n){
    pxf=pp[i*3]; pyf=pp[i*3+1]; pzf=pp[i*3+2];
    px=(double)pxf; py=(double)pyf; pz=(double)pzf;
  }
  double bd0=INFINITY,bd1=INFINITY,bd2=INFINITY,bd3=INFINITY,bd4=INFINITY,bd5=INFINITY;
  float bd5f=INFINITY;
  int   bi0=0x7fffffff,bi1=0x7fffffff,bi2=0x7fffffff,bi3=0x7fffffff,bi4=0x7fffffff,bi5=0x7fffffff;
  __shared__ float sx[256],sy[256],sz[256];
  for (int base=jlo;base<jhi;base+=256){
    int j=base+threadIdx.x;
    if (j<jhi){ sx[threadIdx.x]=pp[j*3]; sy[threadIdx.x]=pp[j*3+1]; sz[threadIdx.x]=pp[j*3+2]; }
    __syncthreads();
    int lim=jhi-base; if (lim>256) lim=256;
    if (i<n){
      for (int t=0;t<lim;t++){
        float dxf=pxf-sx[t], dyf=pyf-sy[t], dzf=pzf-sz[t];
        float d2f=fmaf(dxf,dxf,fmaf(dyf,dyf,dzf*dzf));
        if (d2f<=bd5f){
          double dx=__dsub_rn(px,(double)sx[t]);
          double dy=__dsub_rn(py,(double)sy[t]);
          double dz=__dsub_rn(pz,(double)sz[t]);
          double d2=__dadd_rn(__dadd_rn(__dmul_rn(dx,dx),__dmul_rn(dy,dy)),__dmul_rn(dz,dz));
          if (d2<bd5){
            int id=base+t;
            if (d2<bd4){ bd5=bd4; bi5=bi4;
              if (d2<bd3){ bd4=bd3; bi4=bi3;
                if (d2<bd2){ bd3=bd2; bi3=bi2;
                  if (d2<bd1){ bd2=bd1; bi2=bi1;
                    if (d2<bd0){ bd1=bd0; bi1=bi0; bd0=d2; bi0=id; }
                    else { bd1=d2; bi1=id; }
                  } else { bd2=d2; bi2=id; }
                } else { bd3=d2; bi3=id; }
              } else { bd4=d2; bi4=id; }
            } else { bd5=d2; bi5=id; }
            bd5f=(float)(bd5*1.00001);
          }
        }
      }
    }
    __syncthreads();
  }
  if (i<n){
    size_t o=(((size_t)b*NCH+ch)*n+i)*KNN;
    dcand[o+0]=bd0; dcand[o+1]=bd1; dcand[o+2]=bd2; dcand[o+3]=bd3; dcand[o+4]=bd4; dcand[o+5]=bd5;
    icand[o+0]=bi0; icand[o+1]=bi1; icand[o+2]=bi2; icand[o+3]=bi3; icand[o+4]=bi4; icand[o+5]=bi5;
  }
}

// ---------------- knn merge (+ zero cnt/cur for the CSR pass) ----------------
__global__ void k_knn_merge(const double* __restrict__ dcand, const int* __restrict__ icand,
                            int* __restrict__ nbr, int* __restrict__ cnt, int* __restrict__ cur,
                            int n){
  int t=blockIdx.x*256+threadIdx.x;
  if (t>=BB*n) return;
  cnt[t]=0; cur[t]=0;
  int b=t/n, i=t-b*n;
  double cd[NCH*KNN]; int ci[NCH*KNN];
  #pragma unroll
  for (int ch=0;ch<NCH;ch++){
    size_t o=(((size_t)b*NCH+ch)*n+i)*KNN;
    #pragma unroll
    for (int k=0;k<KNN;k++){ cd[ch*KNN+k]=dcand[o+k]; ci[ch*KNN+k]=icand[o+k]; }
  }
  int* out=nbr+(size_t)t*KNN;
  #pragma unroll
  for (int k=0;k<KNN;k++){
    int best=0;
    for (int q=1;q<NCH*KNN;q++){
      bool lt=(cd[q]<cd[best])||(cd[q]==cd[best]&&ci[q]<ci[best]);
      if (lt) best=q;
    }
    out[k]=ci[best];
    cd[best]=INFINITY; ci[best]=0x7fffffff;
  }
}

// ---------------- edge weights + validity + CSR count ----------------
__global__ void k_edge(const float* __restrict__ posf, const int* __restrict__ nbr,
                       float* __restrict__ w1, float* __restrict__ w2,
                       unsigned char* __restrict__ val2, int* __restrict__ cnt,
                       const float* __restrict__ W1, const float* __restrict__ b1,
                       const float* __restrict__ g,  const float* __restrict__ be,
                       const float* __restrict__ m,  const float* __restrict__ v,
                       const float* __restrict__ W2, const float* __restrict__ b2p,
                       int n){
  int t=blockIdx.x*256+threadIdx.x;
  if (t>=BB*n*KNN) return;
  int k=t%KNN; int c=(t/KNN)%n; int b=t/(KNN*n);
  const int* nb=nbr+(size_t)b*n*KNN;
  int j=nb[c*KNN+k];
  atomicAdd(&cnt[b*n+j],1);
  bool dup=false;
  #pragma unroll
  for (int kk=0;kk<KNN;kk++) dup=dup||(nb[j*KNN+kk]==c);
  const float* pp=posf+(size_t)b*n*3;
  double dx=__dsub_rn((double)pp[c*3+0],(double)pp[j*3+0]);
  double dy=__dsub_rn((double)pp[c*3+1],(double)pp[j*3+1]);
  double dz=__dsub_rn((double)pp[c*3+2],(double)pp[j*3+2]);
  double d2=__dadd_rn(__dadd_rn(__dmul_rn(dx,dx),__dmul_rn(dy,dy)),__dmul_rn(dz,dz));
  float dd=(float)sqrt(d2);
  float wv;
  if (j==c) wv=1.0f;
  else {
    float acc=b2p[0];
    for (int q=0;q<32;q++){
      float tt=dd*W1[q]+b1[q];
      float r=1.0f/sqrtf(v[q]+1e-5f);
      tt=(tt-m[q])*r*g[q]+be[q];
      tt=fmaxf(tt,0.f);
      acc=fmaf(tt,W2[q],acc);
    }
    wv=fmaxf(acc,0.f);
  }
  w1[t]=wv;
  w2[t]=dup?0.f:wv;
  val2[t]=dup?0:1;
}

// ---------------- reverse CSR ----------------
__global__ void k_csr_scan(const int* __restrict__ cnt, int* __restrict__ offs, int n){
  int b=blockIdx.x, t=threadIdx.x;
  int L=(n+255)/256;
  __shared__ int ssum[256];
  int lo=t*L, hi=lo+L; if (hi>n) hi=n; if (lo>n) lo=n;
  int s=0;
  for (int i=lo;i<hi;i++) s+=cnt[b*n+i];
  ssum[t]=s;
  __syncthreads();
  if (t==0){
    int run=0;
    for (int q=0;q<256;q++){ int vv=ssum[q]; ssum[q]=run; run+=vv; }
  }
  __syncthreads();
  int run=ssum[t];
  for (int i=lo;i<hi;i++){ offs[b*(n+1)+i]=run; run+=cnt[b*n+i]; }
  if (lo<n && hi==n) offs[b*(n+1)+n]=run;
}
__global__ void k_csr_fill(const int* __restrict__ nbr, const int* __restrict__ offs,
                           int* __restrict__ cur, int* __restrict__ rev, int n){
  int t=blockIdx.x*256+threadIdx.x;
  if (t>=BB*n*KNN) return;
  int b=t/(n*KNN); int rem=t-b*n*KNN;
  int d=nbr[t];
  int slot=offs[b*(n+1)+d]+atomicAdd(&cur[b*n+d],1);
  if (slot<0) slot=0;
  if (slot>=n*KNN) slot=n*KNN-1;
  rev[(size_t)b*n*KNN+slot]=rem;
}
__global__ void k_sortdeg(int* __restrict__ rev, const int* __restrict__ offs,
                          const float* __restrict__ w1, const float* __restrict__ w2,
                          float* __restrict__ dis, int n){
  int t=blockIdx.x*256+threadIdx.x;
  if (t>=BB*n) return;
  int b=t/n, d=t-b*n;
  size_t base=(size_t)b*n*KNN;
  int lo=offs[b*(n+1)+d], hi=offs[b*(n+1)+d+1];
  for (int a2=lo+1;a2<hi;a2++){
    int vv=rev[base+a2]; int p=a2;
    while (p>lo && rev[base+p-1]>vv){ rev[base+p]=rev[base+p-1]; p--; }
    rev[base+p]=vv;
  }
  float s=0.f;
  #pragma unroll
  for (int k=0;k<KNN;k++) s+=w1[(size_t)t*KNN+k];
  for (int sl=lo;sl<hi;sl++) s+=w2[base+rev[base+sl]];
  dis[t]=1.0f/sqrtf(fmaxf(s,1e-12f));
}

// ---------------- weighted nbr sum (float4, XCD-local) ----------------
template<int MODE,int RAW>
__global__ void k_nbrsum(const float* __restrict__ Hin, const float* __restrict__ w1,
                         const float* __restrict__ w2, const int* __restrict__ nbr,
                         const int* __restrict__ rev, const int* __restrict__ offs,
                         const float* __restrict__ dis, const void* __restrict__ xraw,
                         const int* __restrict__ flag,
                         const int* __restrict__ cum, float* __restrict__ outp, int n){
  int b,d;
  xcd_map(blockIdx.x,threadIdx.x>>6,n,b,d);
  int lane=threadIdx.x&63;
  if (d>=n) return;
  int wid=b*n+d;
  int fl=flag[0];
  const float* Hb=Hin+(size_t)b*n*HD;
  float4 a=make_float4(0.f,0.f,0.f,0.f);
  float dd=(MODE==0)?dis[wid]:0.f;
  int c4=lane*4;
  #pragma unroll
  for (int k=0;k<KNN;k++){
    int sN=nbr[(size_t)wid*KNN+k];
    float wv=w1[(size_t)wid*KNN+k];
    float nm=(MODE==0)?dis[b*n+sN]*wv*dd:wv;
    float4 r = RAW ? loadx4(xraw,fl,((size_t)b*n+sN)*HD+c4)
                   : *(const float4*)(Hb+(size_t)sN*HD+c4);
    a.x=fmaf(nm,r.x,a.x); a.y=fmaf(nm,r.y,a.y); a.z=fmaf(nm,r.z,a.z); a.w=fmaf(nm,r.w,a.w);
  }
  size_t rbase=(size_t)b*n*KNN;
  int lo=offs[b*(n+1)+d], hi=offs[b*(n+1)+d+1];
  for (int sl=lo;sl<hi;sl++){
    int e=rev[rbase+sl];
    int sN=e/KNN;
    float wv=w2[rbase+e];
    float nm=(MODE==0)?dis[b*n+sN]*wv*dd:wv;
    float4 r = RAW ? loadx4(xraw,fl,((size_t)b*n+sN)*HD+c4)
                   : *(const float4*)(Hb+(size_t)sN*HD+c4);
    a.x=fmaf(nm,r.x,a.x); a.y=fmaf(nm,r.y,a.y); a.z=fmaf(nm,r.z,a.z); a.w=fmaf(nm,r.w,a.w);
  }
  if (MODE==0){
    float4 xr=loadx4(xraw,fl,((size_t)b*NMAX+cum[b*NMAX+d])*HD+c4);
    a.x=0.8f*a.x+0.2f*xr.x; a.y=0.8f*a.y+0.2f*xr.y;
    a.z=0.8f*a.z+0.2f*xr.z; a.w=0.8f*a.w+0.2f*xr.w;
  }
  *(float4*)(outp+(size_t)wid*HD+c4)=a;
}

// ---------------- unified panel GEMM, 8x8 thread tile (proven r12-14 form) ----------------
__global__ void k_mm(const float* __restrict__ A1, const float* __restrict__ B1,
                     const float* __restrict__ A2, const float* __restrict__ B2,
                     const float* __restrict__ bias, int relu,
                     float* __restrict__ Cout, int M){
  __shared__ __align__(16) float As[16][68];
  __shared__ __align__(16) float Bs[16][260];
  int tid=threadIdx.x, bm=blockIdx.x;
  int tr=tid>>5, tc=tid&31;
  float acc[8][8];
  #pragma unroll
  for (int i=0;i<8;i++){
    #pragma unroll
    for (int j=0;j<8;j++) acc[i][j]=0.f;
  }
  int l=tid*4;
  int ar=l>>4, ak=l&15;
  int arow=bm*64+ar;
  int KT = A2 ? 512 : 256;
  for (int k0=0;k0<KT;k0+=16){
    const float* Asrc=(k0<HD)?A1:A2;
    const float* Bsrc=(k0<HD)?B1:B2;
    int kc=k0&(HD-1);
    if (arow<M){
      float4 a4=*(const float4*)(Asrc+(size_t)arow*HD+kc+ak);
      As[ak][ar]=a4.x; As[ak+1][ar]=a4.y; As[ak+2][ar]=a4.z; As[ak+3][ar]=a4.w;
    } else {
      As[ak][ar]=0.f; As[ak+1][ar]=0.f; As[ak+2][ar]=0.f; As[ak+3][ar]=0.f;
    }
    #pragma unroll
    for (int c=0;c<4;c++){
      int idx=c*256+tid;
      int rkk=idx>>6, cc=(idx&63)*4;
      *(float4*)&Bs[rkk][cc]=*(const float4*)(Bsrc+(size_t)(kc+rkk)*HD+cc);
    }
    __syncthreads();
    #pragma unroll
    for (int kk=0;kk<16;kk++){
      float af[8], bf[8];
      *(float4*)&af[0]=*(const float4*)&As[kk][tr*8];
      *(float4*)&af[4]=*(const float4*)&As[kk][tr*8+4];
      *(float4*)&bf[0]=*(const float4*)&Bs[kk][tc*8];
      *(float4*)&bf[4]=*(const float4*)&Bs[kk][tc*8+4];
      #pragma unroll
      for (int i=0;i<8;i++){
        #pragma unroll
        for (int j=0;j<8;j++) acc[i][j]=fmaf(af[i],bf[j],acc[i][j]);
      }
    }
    __syncthreads();
  }
  #pragma unroll
  for (int i=0;i<8;i++){
    int grow=bm*64+tr*8+i;
    if (grow>=M) continue;
    #pragma unroll
    for (int j=0;j<8;j++){
      int gcol=tc*8+j;
      float v=acc[i][j];
      if (bias) v+=bias[gcol];
      if (relu) v=fmaxf(v,0.f);
      Cout[(size_t)grow*HD+gcol]=v;
    }
  }
}

// ---------------- va = rowdot(Wlin, wa); va[256] = blin . wa ----------------
__global__ void k_va(const float* __restrict__ Wlin, const float* __restrict__ wa,
                     const float* __restrict__ blin, float* __restrict__ va){
  int i=threadIdx.x;
  float acc=0.f;
  for (int j=0;j<HD;j++) acc=fmaf(Wlin[(size_t)i*HD+j],wa[j],acc);
  va[i]=acc;
  if (i==0){
    float c=0.f;
    for (int j=0;j<HD;j++) c=fmaf(blin[j],wa[j],c);
    va[256]=c;
  }
}

// ---------------- fused: pb, qd (XCD-local) ----------------
__global__ void k_qd(const float* __restrict__ T, const float* __restrict__ wb,
                     const float* __restrict__ va, const int* __restrict__ nbr,
                     const int* __restrict__ rev, const int* __restrict__ offs,
                     const unsigned char* __restrict__ val2,
                     float* __restrict__ pb, float* __restrict__ qd, int n){
  int b,d;
  xcd_map(blockIdx.x,threadIdx.x>>6,n,b,d);
  int lane=threadIdx.x&63;
  if (d>=n) return;
  int wid=b*n+d;
  int c4=lane*4;
  float4 r1=*(const float4*)(T+(size_t)wid*HD+c4);
  float4 wb4=*(const float4*)(wb+c4);
  float p=r1.x*wb4.x+r1.y*wb4.y+r1.z*wb4.z+r1.w*wb4.w;
  const float* Tb=T+(size_t)b*n*HD;
  float4 m4=make_float4(-INFINITY,-INFINITY,-INFINITY,-INFINITY);
  #pragma unroll
  for (int k=0;k<KNN;k++){
    int sN=nbr[(size_t)wid*KNN+k];
    float4 r=*(const float4*)(Tb+(size_t)sN*HD+c4);
    m4.x=fmaxf(m4.x,r.x); m4.y=fmaxf(m4.y,r.y); m4.z=fmaxf(m4.z,r.z); m4.w=fmaxf(m4.w,r.w);
  }
  size_t rbase=(size_t)b*n*KNN;
  int lo=offs[b*(n+1)+d], hi=offs[b*(n+1)+d+1];
  for (int sl=lo;sl<hi;sl++){
    int e=rev[rbase+sl];
    if (!val2[rbase+e]) continue;
    int sN=e/KNN;
    float4 r=*(const float4*)(Tb+(size_t)sN*HD+c4);
    m4.x=fmaxf(m4.x,r.x); m4.y=fmaxf(m4.y,r.y); m4.z=fmaxf(m4.z,r.z); m4.w=fmaxf(m4.w,r.w);
  }
  float4 va4=*(const float4*)(va+c4);
  float q=va4.x*m4.x+va4.y*m4.y+va4.z*m4.z+va4.w*m4.w;
  #pragma unroll
  for (int o=32;o>0;o>>=1){ p+=__shfl_xor(p,o); q+=__shfl_xor(q,o); }
  if (lane==0){ pb[wid]=p; qd[wid]=q+va[256]; }
}

// ---------------- attention softmax + xn + fused LEConv dots (XCD-local) ----------------
__global__ void k_attxn(const float* __restrict__ Hin, const float* __restrict__ pb,
                        const float* __restrict__ qd, const int* __restrict__ nbr,
                        const int* __restrict__ rev, const int* __restrict__ offs,
                        const unsigned char* __restrict__ val2, const float* __restrict__ abatt,
                        const float* __restrict__ lW1, const float* __restrict__ lb1,
                        const float* __restrict__ lW2, const float* __restrict__ lW3,
                        const float* __restrict__ lb3,
                        float* __restrict__ av, float* __restrict__ bbv, float* __restrict__ l3v,
                        float* __restrict__ Tout, int n){
  int b,d;
  xcd_map(blockIdx.x,threadIdx.x>>6,n,b,d);
  int lane=threadIdx.x&63;
  if (d>=n) return;
  int wid=b*n+d;
  float batt=abatt[0];
  float qs=qd[wid];
  const float* Hb=Hin+(size_t)b*n*HD;
  int c4=lane*4;
  size_t rbase=(size_t)b*n*KNN;
  int lo=offs[b*(n+1)+d], hi=offs[b*(n+1)+d+1];
  float smax=-INFINITY;
  #pragma unroll
  for (int k=0;k<KNN;k++){
    int sN=nbr[(size_t)wid*KNN+k];
    float sc=qs+pb[b*n+sN]+batt;
    sc=sc>=0.f?sc:0.2f*sc;
    smax=fmaxf(smax,sc);
  }
  for (int sl=lo;sl<hi;sl++){
    int e=rev[rbase+sl];
    if (!val2[rbase+e]) continue;
    int sN=e/KNN;
    float sc=qs+pb[b*n+sN]+batt;
    sc=sc>=0.f?sc:0.2f*sc;
    smax=fmaxf(smax,sc);
  }
  float es=0.f;
  float4 a=make_float4(0.f,0.f,0.f,0.f);
  #pragma unroll
  for (int k=0;k<KNN;k++){
    int sN=nbr[(size_t)wid*KNN+k];
    float sc=qs+pb[b*n+sN]+batt;
    sc=sc>=0.f?sc:0.2f*sc;
    float e2=expf(sc-smax);
    es+=e2;
    float4 r=*(const float4*)(Hb+(size_t)sN*HD+c4);
    a.x=fmaf(e2,r.x,a.x); a.y=fmaf(e2,r.y,a.y); a.z=fmaf(e2,r.z,a.z); a.w=fmaf(e2,r.w,a.w);
  }
  for (int sl=lo;sl<hi;sl++){
    int e=rev[rbase+sl];
    if (!val2[rbase+e]) continue;
    int sN=e/KNN;
    float sc=qs+pb[b*n+sN]+batt;
    sc=sc>=0.f?sc:0.2f*sc;
    float e2=expf(sc-smax);
    es+=e2;
    float4 r=*(const float4*)(Hb+(size_t)sN*HD+c4);
    a.x=fmaf(e2,r.x,a.x); a.y=fmaf(e2,r.y,a.y); a.z=fmaf(e2,r.z,a.z); a.w=fmaf(e2,r.w,a.w);
  }
  float inv=1.f/es;
  a.x*=inv; a.y*=inv; a.z*=inv; a.w*=inv;
  *(float4*)(Tout+(size_t)wid*HD+c4)=a;
  float4 w1v=*(const float4*)(lW1+c4);
  float4 w2v=*(const float4*)(lW2+c4);
  float4 w3v=*(const float4*)(lW3+c4);
  float s1=a.x*w1v.x+a.y*w1v.y+a.z*w1v.z+a.w*w1v.w;
  float s2=a.x*w2v.x+a.y*w2v.y+a.z*w2v.z+a.w*w2v.w;
  float s3=a.x*w3v.x+a.y*w3v.y+a.z*w3v.z+a.w*w3v.w;
  #pragma unroll
  for (int o=32;o>0;o>>=1){ s1+=__shfl_xor(s1,o); s2+=__shfl_xor(s2,o); s3+=__shfl_xor(s3,o); }
  if (lane==0){ av[wid]=s1+lb1[0]; bbv[wid]=s2; l3v[wid]=s3+lb3[0]; }
}

__global__ void k_fit(const float* __restrict__ av, const float* __restrict__ bbv,
                      const float* __restrict__ l3v, const int* __restrict__ nbr,
                      const int* __restrict__ rev, const int* __restrict__ offs,
                      const unsigned char* __restrict__ val2, float* __restrict__ fit, int n){
  int t=blockIdx.x*256+threadIdx.x;
  if (t>=BB*n) return;
  int b=t/n, d=t-b*n;
  size_t rbase=(size_t)b*n*KNN;
  float ms=0.f; int cv=KNN;
  #pragma unroll
  for (int k=0;k<KNN;k++) ms+=av[b*n+nbr[(size_t)t*KNN+k]];
  int lo=offs[b*(n+1)+d], hi=offs[b*(n+1)+d+1];
  for (int sl=lo;sl<hi;sl++){
    int e=rev[rbase+sl];
    if (val2[rbase+e]){ ms+=av[b*n+e/KNN]; cv++; }
  }
  float z=ms-(float)cv*bbv[t]+l3v[t];
  fit[t]=1.f/(1.f+expf(-z));
}

// ---------------- top-k by rank-counting, LDS-staged ----------------
__global__ void k_rank(const float* __restrict__ fit, float* __restrict__ svl,
                       int* __restrict__ sid, int n, int kp){
  __shared__ float sf[2048];
  int b=blockIdx.y;
  int i=blockIdx.x*256+threadIdx.x;
  const float* fb=fit+(size_t)b*n;
  for (int j=threadIdx.x;j<n;j+=256) sf[j]=fb[j];
  __syncthreads();
  if (i>=n) return;
  float fi=sf[i];
  int rank=0;
  for (int j=0;j<n;j++){
    float fj=sf[j];
    if (fj>fi || (fj==fi && j<i)) rank++;
  }
  if (rank<kp){ svl[b*NMAX+rank]=fi; sid[b*NMAX+rank]=i; }
}

// ---------------- pool gather (float4) ----------------
__global__ void k_pool(const float* __restrict__ T, const float* __restrict__ svl,
                       const int* __restrict__ sid, const int* __restrict__ cumA,
                       int* __restrict__ cumB, float* __restrict__ Hout, int n, int kp){
  int wid=blockIdx.x*4+(threadIdx.x>>6);
  int lane=threadIdx.x&63;
  if (wid>=BB*kp) return;
  int b=wid/kp, j=wid-b*kp;
  int srcn=sid[b*NMAX+j];
  if (srcn<0) srcn=0;
  if (srcn>=n) srcn=n-1;
  float vv=svl[b*NMAX+j];
  int c4=lane*4;
  float4 r=*(const float4*)(T+((size_t)b*n+srcn)*HD+c4);
  r.x*=vv; r.y*=vv; r.z*=vv; r.w*=vv;
  *(float4*)(Hout+((size_t)b*kp+j)*HD+c4)=r;
  if (lane==0) cumB[b*NMAX+j]=cumA[b*NMAX+srcn];
}

// ---------------- readout: [mean | max], 4-wave parallel ----------------
__global__ void k_readout(const float* __restrict__ Hb, float* __restrict__ ro, int n){
  __shared__ float ss[4][256], sm[4][256];
  int b=blockIdx.x, tid=threadIdx.x;
  int wv=tid>>6, lane=tid&63;
  int c4=lane*4;
  float4 s=make_float4(0.f,0.f,0.f,0.f);
  float4 m=make_float4(-INFINITY,-INFINITY,-INFINITY,-INFINITY);
  for (int i=wv;i<n;i+=4){
    float4 v=*(const float4*)(Hb+((size_t)b*n+i)*HD+c4);
    s.x+=v.x; s.y+=v.y; s.z+=v.z; s.w+=v.w;
    m.x=fmaxf(m.x,v.x); m.y=fmaxf(m.y,v.y); m.z=fmaxf(m.z,v.z); m.w=fmaxf(m.w,v.w);
  }
  *(float4*)&ss[wv][c4]=s;
  *(float4*)&sm[wv][c4]=m;
  __syncthreads();
  int h=tid;
  float acc=ss[0][h]+ss[1][h]+ss[2][h]+ss[3][h];
  float mx=fmaxf(fmaxf(sm[0][h],sm[1][h]),fmaxf(sm[2][h],sm[3][h]));
  ro[b*512+h]=acc/(float)n;
  ro[b*512+256+h]=mx;
}

// ---------------- final ----------------
__global__ void k_final(const float* __restrict__ Hb, const float* __restrict__ gW,
                        const float* __restrict__ gb, const float* __restrict__ nW,
                        const float* __restrict__ nbias, const float* __restrict__ ro0,
                        const float* __restrict__ ro1, float* __restrict__ outp, int n){
  int b=blockIdx.x, tid=threadIdx.x;
  int wv=tid>>6, lane=tid&63;
  __shared__ float gate[64];
  for (int i=wv;i<n;i+=4){
    const float* r=Hb+((size_t)b*n+i)*HD;
    float p=0.f;
    for (int h=lane;h<HD;h+=64) p=fmaf(r[h],gW[h],p);
    #pragma unroll
    for (int o=32;o>0;o>>=1) p+=__shfl_xor(p,o);
    if (lane==0) gate[i]=p+gb[0];
  }
  __syncthreads();
  if (tid==0){
    float mx=-INFINITY;
    for (int i=0;i<n;i++) mx=fmaxf(mx,gate[i]);
    float sm=0.f;
    for (int i=0;i<n;i++){ gate[i]=expf(gate[i]-mx); sm+=gate[i]; }
    float inv=1.f/sm;
    for (int i=0;i<n;i++) gate[i]*=inv;
  }
  __syncthreads();
  if (tid<OUTD){
    float acc=0.f;
    for (int i=0;i<n;i++){
      const float* r=Hb+((size_t)b*n+i)*HD;
      float dot=0.f;
      for (int h=0;h<HD;h++) dot=fmaf(r[h],nW[(size_t)h*OUTD+tid],dot);
      acc=fmaf(gate[i],dot+nbias[tid],acc);
    }
    outp[(size_t)b*1152+tid]=acc;
  }
  for (int q=tid;q<512;q+=256){
    outp[(size_t)b*1152+128+q]=ro1[b*512+q];
    outp[(size_t)b*1152+640+q]=ro0[b*512+q];
  }
}

// =======================================================================
extern "C" void kernel_launch(void* const* d_in, const int* in_sizes, int n_in,
                              void* d_out, int out_size, void* d_ws, size_t ws_size,
                              hipStream_t stream){
  if (n_in<27) return;
  if (in_sizes[0]!=BB*NMAX*HD || in_sizes[1]!=BB*NMAX*3) return;
  float* outp=(float*)d_out;
  (void)out_size;

  char* p=(char*)d_ws;
  auto carve=[&](size_t bytes)->char*{ char* r=p; p+=((bytes+255)/256)*256; return r; };
  float* posF=(float*)carve((size_t)BB*NMAX*3*4);
  float* posf=(float*)carve((size_t)BB*NMAX*3*4);
  float* Hbuf=(float*)carve((size_t)BB*NMAX*HD*4);
  float* Tbuf=(float*)carve((size_t)BB*NMAX*HD*4);
  static const int wcnt[25]={262144,128,128,128,128,128,128,128,4,
                             196608,768,196608,196608,768,1536,3,
                             768,3,768,768,3,256,1,32768,128};
  int woff[25]; int wtot=0;
  for (int i=0;i<25;i++){ woff[i]=wtot; wtot+=(wcnt[i]+63)&~63; }
  float* wsW=(float*)carve((size_t)wtot*4);
  int*   nbr =(int*)  carve((size_t)BB*NMAX*KNN*4);
  int*   rev =(int*)  carve((size_t)BB*NMAX*KNN*4);
  float* w1  =(float*)carve((size_t)BB*NMAX*KNN*4);
  float* w2  =(float*)carve((size_t)BB*NMAX*KNN*4);
  unsigned char* val2=(unsigned char*)carve((size_t)BB*NMAX*KNN);
  int* cnt  =(int*)carve((size_t)BB*NMAX*4);
  int* offs =(int*)carve((size_t)BB*(NMAX+1)*4);
  int* cur  =(int*)carve((size_t)BB*NMAX*4);
  float* dis=(float*)carve((size_t)BB*NMAX*4);
  float* pb =(float*)carve((size_t)BB*NMAX*4);
  float* qd =(float*)carve((size_t)BB*NMAX*4);
  float* av =(float*)carve((size_t)BB*NMAX*4);
  float* bbv=(float*)carve((size_t)BB*NMAX*4);
  float* l3v=(float*)carve((size_t)BB*NMAX*4);
  float* fit=(float*)carve((size_t)BB*NMAX*4);
  float* svl=(float*)carve((size_t)BB*NMAX*4);
  int*   sid=(int*)  carve((size_t)BB*NMAX*4);
  int* cumA =(int*)carve((size_t)BB*NMAX*4);
  int* cumB =(int*)carve((size_t)BB*NMAX*4);
  int* flag =(int*)carve(256);
  float* va =(float*)carve(272*4);
  float* ro0=(float*)carve((size_t)BB*512*4);
  float* ro1=(float*)carve((size_t)BB*512*4);
  size_t need=(size_t)(p-(char*)d_ws);
  if (ws_size<need) return;

  double* dcand=(double*)Tbuf;
  int*    icand=(int*)((char*)Tbuf + (size_t)BB*NCH*NMAX*KNN*8);

  k_detect<<<1,256,0,stream>>>(d_in[0],flag);
  k_cvtpos<<<(BB*NMAX*3+255)/256,256,0,stream>>>(d_in[1],flag,posF);
  {
    WTab tab;
    int maxc=0;
    for (int i=0;i<25;i++){ tab.src[i]=d_in[2+i]; tab.cnt[i]=wcnt[i]; tab.dst[i]=woff[i]; if (wcnt[i]>maxc) maxc=wcnt[i]; }
    k_cvtw<<<dim3((maxc+255)/256,25),256,0,stream>>>(tab,flag,wsW);
  }
  k_initcum<<<(BB*NMAX+255)/256,256,0,stream>>>(cumA);

  const int NS[4]={2048,308,77,39};
  const int KP[3]={308,77,39};

  for (int s=0;s<4;s++){
    int n=NS[s]; int M=BB*n;
    int gG=BB*((n+3)/4);
    const float* wconv =wsW+woff[0]+(size_t)s*65536;
    const float* eW1p  =wsW+woff[1]+s*32;
    const float* eb1p  =wsW+woff[2]+s*32;
    const float* gp    =wsW+woff[3]+s*32;
    const float* bep   =wsW+woff[4]+s*32;
    const float* mp    =wsW+woff[5]+s*32;
    const float* vp    =wsW+woff[6]+s*32;
    const float* W2p   =wsW+woff[7]+s*32;
    const float* b2p   =wsW+woff[8]+s;
    const float* aWrelp=wsW+woff[9]+(size_t)s*65536;
    const float* abrelp=wsW+woff[10]+s*256;
    const float* aWrootp=wsW+woff[11]+(size_t)s*65536;
    const float* aWlinp=wsW+woff[12]+(size_t)s*65536;
    const float* ablinp=wsW+woff[13]+s*256;
    const float* wap   =wsW+woff[14]+s*512;
    const float* wbp   =wsW+woff[14]+s*512+256;
    const float* abattp=wsW+woff[15]+s;
    const float* leW1p =wsW+woff[16]+s*256;
    const float* leb1p =wsW+woff[17]+s;
    const float* leW2p =wsW+woff[18]+s*256;
    const float* leW3p =wsW+woff[19]+s*256;
    const float* leb3p =wsW+woff[20]+s;

    const float* pf;
    if (s==0){
      pf=posF;
    } else {
      k_gatherpos<<<(BB*n*3+255)/256,256,0,stream>>>(posF,cumA,posf,n);
      pf=posf;
    }
    k_knn_part<<<dim3((n+255)/256,NCH,BB),256,0,stream>>>(pf,dcand,icand,n);
    k_knn_merge<<<(BB*n+255)/256,256,0,stream>>>(dcand,icand,nbr,cnt,cur,n);
    int totE=BB*n*KNN;
    k_edge<<<(totE+255)/256,256,0,stream>>>(pf,nbr,w1,w2,val2,cnt,
        eW1p,eb1p,gp,bep,mp,vp,W2p,b2p,n);
    k_csr_scan<<<BB,256,0,stream>>>(cnt,offs,n);
    k_csr_fill<<<(totE+255)/256,256,0,stream>>>(nbr,offs,cur,rev,n);
    k_sortdeg<<<(BB*n+255)/256,256,0,stream>>>(rev,offs,w1,w2,dis,n);
    if (s==1) k_readout<<<BB,256,0,stream>>>(Hbuf,ro0,n);
    if (s==2) k_readout<<<BB,256,0,stream>>>(Hbuf,ro1,n);
    if (s==0)
      k_nbrsum<0,1><<<gG,256,0,stream>>>(nullptr,w1,w2,nbr,rev,offs,dis,d_in[0],flag,cumA,Tbuf,n);
    else
      k_nbrsum<0,0><<<gG,256,0,stream>>>(Hbuf,w1,w2,nbr,rev,offs,dis,d_in[0],flag,cumA,Tbuf,n);
    k_mm<<<(M+63)/64,256,0,stream>>>(Tbuf,wconv,(const float*)nullptr,(const float*)nullptr,
                                     (const float*)nullptr,1,Hbuf,M);
    if (s<3){
      int kp=KP[s];
      k_nbrsum<1,0><<<gG,256,0,stream>>>(Hbuf,w1,w2,nbr,rev,offs,dis,d_in[0],flag,cumA,Tbuf,n);
      k_mm<<<(M+63)/64,256,0,stream>>>(Tbuf,aWrelp,Hbuf,aWrootp,abrelp,0,Tbuf,M);
      k_va<<<1,256,0,stream>>>(aWlinp,wap,ablinp,va);
      k_qd<<<gG,256,0,stream>>>(Tbuf,wbp,va,nbr,rev,offs,val2,pb,qd,n);
      k_attxn<<<gG,256,0,stream>>>(Hbuf,pb,qd,nbr,rev,offs,val2,abattp,
                                   leW1p,leb1p,leW2p,leW3p,leb3p,av,bbv,l3v,Tbuf,n);
      k_fit<<<(BB*n+255)/256,256,0,stream>>>(av,bbv,l3v,nbr,rev,offs,val2,fit,n);
      k_rank<<<dim3((n+255)/256,BB),256,0,stream>>>(fit,svl,sid,n,kp);
      k_pool<<<(BB*kp+3)/4,256,0,stream>>>(Tbuf,svl,sid,cumA,cumB,Hbuf,n,kp);
      { int* t=cumA; cumA=cumB; cumB=t; }
    }
  }
  k_final<<<BB,256,0,stream>>>(Hbuf,wsW+woff[21],wsW+woff[22],wsW+woff[23],wsW+woff[24],
                               ro0,ro1,outp,NS[3]);
}

// Round 17
// 2008.526 us; speedup vs baseline: 1.1361x; 1.0057x over previous
//
#include <hip/hip_runtime.h>
#include <hip/hip_bf16.h>
#include <math.h>

#define BB 32
#define NMAX 2048
#define HD 256
#define KNN 6
#define OUTD 128
#define NCH 8

typedef __hip_bfloat16 bf16;

// XCD-locality mapping: block g, wave w -> (batch, node).
__device__ __forceinline__ void xcd_map(int g, int wave, int n, int& b, int& d){
  int P=(n+3)>>2;
  int r=g&7, q=g>>3;
  b=r+8*(q/P);
  d=(q%P)*4+wave;
}

// ---------------- dtype detect ----------------
__global__ void k_detect(const void* __restrict__ x, int* __restrict__ flag){
  __shared__ int cnt_s;
  if (threadIdx.x==0) cnt_s=0;
  __syncthreads();
  const unsigned short* u=(const unsigned short*)x;
  int c=0;
  for (int i=threadIdx.x;i<4096;i+=256){
    int e=(u[i]>>7)&0xFF;
    if (e>=0xC0) c++;
  }
  atomicAdd(&cnt_s,c);
  __syncthreads();
  if (threadIdx.x==0) flag[0]=(cnt_s>32)?1:0;
}

__device__ __forceinline__ float loadx(const void* x, int fl, size_t idx){
  if (fl) return ((const float*)x)[idx];
  unsigned short u=((const unsigned short*)x)[idx];
  return __uint_as_float(((unsigned)u)<<16);
}
__device__ __forceinline__ float4 loadx4(const void* x, int fl, size_t idx){
  if (fl) return *(const float4*)((const float*)x+idx);
  float4 r;
  r.x=loadx(x,0,idx); r.y=loadx(x,0,idx+1); r.z=loadx(x,0,idx+2); r.w=loadx(x,0,idx+3);
  return r;
}

__global__ void k_cvtpos(const void* __restrict__ pos, const int* __restrict__ flag,
                         float* __restrict__ posF){
  int t=blockIdx.x*256+threadIdx.x;
  if (t>=BB*NMAX*3) return;
  posF[t]=loadx(pos,flag[0],t);
}
struct WTab { const void* src[25]; int cnt[25]; int dst[25]; };
__global__ void k_cvtw(WTab tab, const int* __restrict__ flag, float* __restrict__ wsW){
  int seg=blockIdx.y;
  int t=blockIdx.x*256+threadIdx.x;
  if (t>=tab.cnt[seg]) return;
  wsW[tab.dst[seg]+t]=loadx(tab.src[seg],flag[0],t);
}

__global__ void k_initcum(int* __restrict__ cum){
  int t=blockIdx.x*256+threadIdx.x;
  if (t<BB*NMAX) cum[t]=t%NMAX;
}
__global__ void k_gatherpos(const float* __restrict__ posF, const int* __restrict__ cum,
                            float* __restrict__ posf, int n){
  int t=blockIdx.x*256+threadIdx.x;
  if (t>=BB*n*3) return;
  int c=t%3, i=(t/3)%n, b=t/(3*n);
  posf[t]=posF[((size_t)b*NMAX+cum[b*NMAX+i])*3+c];
}

// ---------------- knn part: f32 prune + exact f64 verify ----------------
__global__ void k_knn_part(const float* __restrict__ posf, double* __restrict__ dcand,
                           int* __restrict__ icand, int n){
  int b=blockIdx.z, ch=blockIdx.y;
  int i=blockIdx.x*256+threadIdx.x;
  const float* pp=posf+(size_t)b*n*3;
  int cs=(n+NCH-1)/NCH;
  int jlo=ch*cs, jhi=jlo+cs; if (jhi>n) jhi=n;
  float pxf=0.f,pyf=0.f,pzf=0.f;
  double px=0.0,py=0.0,pz=0.0;
  if (i<n){
    pxf=pp[i*3]; pyf=pp[i*3+1]; pzf=pp[i*3+2];
    px=(double)pxf; py=(double)pyf; pz=(double)pzf;
  }
  double bd0=INFINITY,bd1=INFINITY,bd2=INFINITY,bd3=INFINITY,bd4=INFINITY,bd5=INFINITY;
  float bd5f=INFINITY;
  int   bi0=0x7fffffff,bi1=0x7fffffff,bi2=0x7fffffff,bi3=0x7fffffff,bi4=0x7fffffff,bi5=0x7fffffff;
  __shared__ float sx[256],sy[256],sz[256];
  for (int base=jlo;base<jhi;base+=256){
    int j=base+threadIdx.x;
    if (j<jhi){ sx[threadIdx.x]=pp[j*3]; sy[threadIdx.x]=pp[j*3+1]; sz[threadIdx.x]=pp[j*3+2]; }
    __syncthreads();
    int lim=jhi-base; if (lim>256) lim=256;
    if (i<n){
      for (int t=0;t<lim;t++){
        float dxf=pxf-sx[t], dyf=pyf-sy[t], dzf=pzf-sz[t];
        float d2f=fmaf(dxf,dxf,fmaf(dyf,dyf,dzf*dzf));
        if (d2f<=bd5f){
          double dx=__dsub_rn(px,(double)sx[t]);
          double dy=__dsub_rn(py,(double)sy[t]);
          double dz=__dsub_rn(pz,(double)sz[t]);
          double d2=__dadd_rn(__dadd_rn(__dmul_rn(dx,dx),__dmul_rn(dy,dy)),__dmul_rn(dz,dz));
          if (d2<bd5){
            int id=base+t;
            if (d2<bd4){ bd5=bd4; bi5=bi4;
              if (d2<bd3){ bd4=bd3; bi4=bi3;
                if (d2<bd2){ bd3=bd2; bi3=bi2;
                  if (d2<bd1){ bd2=bd1; bi2=bi1;
                    if (d2<bd0){ bd1=bd0; bi1=bi0; bd0=d2; bi0=id; }
                    else { bd1=d2; bi1=id; }
                  } else { bd2=d2; bi2=id; }
                } else { bd3=d2; bi3=id; }
              } else { bd4=d2; bi4=id; }
            } else { bd5=d2; bi5=id; }
            bd5f=(float)(bd5*1.00001);
          }
        }
      }
    }
    __syncthreads();
  }
  if (i<n){
    size_t o=(((size_t)b*NCH+ch)*n+i)*KNN;
    dcand[o+0]=bd0; dcand[o+1]=bd1; dcand[o+2]=bd2; dcand[o+3]=bd3; dcand[o+4]=bd4; dcand[o+5]=bd5;
    icand[o+0]=bi0; icand[o+1]=bi1; icand[o+2]=bi2; icand[o+3]=bi3; icand[o+4]=bi4; icand[o+5]=bi5;
  }
}

// ---------------- knn merge (+ zero cnt/cur) ----------------
__global__ void k_knn_merge(const double* __restrict__ dcand, const int* __restrict__ icand,
                            int* __restrict__ nbr, int* __restrict__ cnt, int* __restrict__ cur,
                            int n){
  int t=blockIdx.x*256+threadIdx.x;
  if (t>=BB*n) return;
  cnt[t]=0; cur[t]=0;
  int b=t/n, i=t-b*n;
  double cd[NCH*KNN]; int ci[NCH*KNN];
  #pragma unroll
  for (int ch=0;ch<NCH;ch++){
    size_t o=(((size_t)b*NCH+ch)*n+i)*KNN;
    #pragma unroll
    for (int k=0;k<KNN;k++){ cd[ch*KNN+k]=dcand[o+k]; ci[ch*KNN+k]=icand[o+k]; }
  }
  int* out=nbr+(size_t)t*KNN;
  #pragma unroll
  for (int k=0;k<KNN;k++){
    int best=0;
    for (int q=1;q<NCH*KNN;q++){
      bool lt=(cd[q]<cd[best])||(cd[q]==cd[best]&&ci[q]<ci[best]);
      if (lt) best=q;
    }
    out[k]=ci[best];
    cd[best]=INFINITY; ci[best]=0x7fffffff;
  }
}

// ---------------- edge weights + validity + CSR count ----------------
__global__ void k_edge(const float* __restrict__ posf, const int* __restrict__ nbr,
                       float* __restrict__ w1, float* __restrict__ w2,
                       unsigned char* __restrict__ val2, int* __restrict__ cnt,
                       const float* __restrict__ W1, const float* __restrict__ b1,
                       const float* __restrict__ g,  const float* __restrict__ be,
                       const float* __restrict__ m,  const float* __restrict__ v,
                       const float* __restrict__ W2, const float* __restrict__ b2p,
                       int n){
  int t=blockIdx.x*256+threadIdx.x;
  if (t>=BB*n*KNN) return;
  int k=t%KNN; int c=(t/KNN)%n; int b=t/(KNN*n);
  const int* nb=nbr+(size_t)b*n*KNN;
  int j=nb[c*KNN+k];
  atomicAdd(&cnt[b*n+j],1);
  bool dup=false;
  #pragma unroll
  for (int kk=0;kk<KNN;kk++) dup=dup||(nb[j*KNN+kk]==c);
  const float* pp=posf+(size_t)b*n*3;
  double dx=__dsub_rn((double)pp[c*3+0],(double)pp[j*3+0]);
  double dy=__dsub_rn((double)pp[c*3+1],(double)pp[j*3+1]);
  double dz=__dsub_rn((double)pp[c*3+2],(double)pp[j*3+2]);
  double d2=__dadd_rn(__dadd_rn(__dmul_rn(dx,dx),__dmul_rn(dy,dy)),__dmul_rn(dz,dz));
  float dd=(float)sqrt(d2);
  float wv;
  if (j==c) wv=1.0f;
  else {
    float acc=b2p[0];
    for (int q=0;q<32;q++){
      float tt=dd*W1[q]+b1[q];
      float r=1.0f/sqrtf(v[q]+1e-5f);
      tt=(tt-m[q])*r*g[q]+be[q];
      tt=fmaxf(tt,0.f);
      acc=fmaf(tt,W2[q],acc);
    }
    wv=fmaxf(acc,0.f);
  }
  w1[t]=wv;
  w2[t]=dup?0.f:wv;
  val2[t]=dup?0:1;
}

// ---------------- reverse CSR ----------------
__global__ void k_csr_scan(const int* __restrict__ cnt, int* __restrict__ offs, int n){
  int b=blockIdx.x, t=threadIdx.x;
  int L=(n+255)/256;
  __shared__ int ssum[256];
  int lo=t*L, hi=lo+L; if (hi>n) hi=n; if (lo>n) lo=n;
  int s=0;
  for (int i=lo;i<hi;i++) s+=cnt[b*n+i];
  ssum[t]=s;
  __syncthreads();
  if (t==0){
    int run=0;
    for (int q=0;q<256;q++){ int vv=ssum[q]; ssum[q]=run; run+=vv; }
  }
  __syncthreads();
  int run=ssum[t];
  for (int i=lo;i<hi;i++){ offs[b*(n+1)+i]=run; run+=cnt[b*n+i]; }
  if (lo<n && hi==n) offs[b*(n+1)+n]=run;
}
__global__ void k_csr_fill(const int* __restrict__ nbr, const int* __restrict__ offs,
                           int* __restrict__ cur, int* __restrict__ rev, int n){
  int t=blockIdx.x*256+threadIdx.x;
  if (t>=BB*n*KNN) return;
  int b=t/(n*KNN); int rem=t-b*n*KNN;
  int d=nbr[t];
  int slot=offs[b*(n+1)+d]+atomicAdd(&cur[b*n+d],1);
  if (slot<0) slot=0;
  if (slot>=n*KNN) slot=n*KNN-1;
  rev[(size_t)b*n*KNN+slot]=rem;
}
__global__ void k_sortdeg(int* __restrict__ rev, const int* __restrict__ offs,
                          const float* __restrict__ w1, const float* __restrict__ w2,
                          float* __restrict__ dis, int n){
  int t=blockIdx.x*256+threadIdx.x;
  if (t>=BB*n) return;
  int b=t/n, d=t-b*n;
  size_t base=(size_t)b*n*KNN;
  int lo=offs[b*(n+1)+d], hi=offs[b*(n+1)+d+1];
  for (int a2=lo+1;a2<hi;a2++){
    int vv=rev[base+a2]; int p=a2;
    while (p>lo && rev[base+p-1]>vv){ rev[base+p]=rev[base+p-1]; p--; }
    rev[base+p]=vv;
  }
  float s=0.f;
  #pragma unroll
  for (int k=0;k<KNN;k++) s+=w1[(size_t)t*KNN+k];
  for (int sl=lo;sl<hi;sl++) s+=w2[base+rev[base+sl]];
  dis[t]=1.0f/sqrtf(fmaxf(s,1e-12f));
}

// ---------------- weighted nbr sum (float4, XCD-local) ----------------
template<int MODE,int RAW>
__global__ void k_nbrsum(const float* __restrict__ Hin, const float* __restrict__ w1,
                         const float* __restrict__ w2, const int* __restrict__ nbr,
                         const int* __restrict__ rev, const int* __restrict__ offs,
                         const float* __restrict__ dis, const void* __restrict__ xraw,
                         const int* __restrict__ flag,
                         const int* __restrict__ cum, float* __restrict__ outp, int n){
  int b,d;
  xcd_map(blockIdx.x,threadIdx.x>>6,n,b,d);
  int lane=threadIdx.x&63;
  if (d>=n) return;
  int wid=b*n+d;
  int fl=flag[0];
  const float* Hb=Hin+(size_t)b*n*HD;
  float4 a=make_float4(0.f,0.f,0.f,0.f);
  float dd=(MODE==0)?dis[wid]:0.f;
  int c4=lane*4;
  #pragma unroll
  for (int k=0;k<KNN;k++){
    int sN=nbr[(size_t)wid*KNN+k];
    float wv=w1[(size_t)wid*KNN+k];
    float nm=(MODE==0)?dis[b*n+sN]*wv*dd:wv;
    float4 r = RAW ? loadx4(xraw,fl,((size_t)b*n+sN)*HD+c4)
                   : *(const float4*)(Hb+(size_t)sN*HD+c4);
    a.x=fmaf(nm,r.x,a.x); a.y=fmaf(nm,r.y,a.y); a.z=fmaf(nm,r.z,a.z); a.w=fmaf(nm,r.w,a.w);
  }
  size_t rbase=(size_t)b*n*KNN;
  int lo=offs[b*(n+1)+d], hi=offs[b*(n+1)+d+1];
  for (int sl=lo;sl<hi;sl++){
    int e=rev[rbase+sl];
    int sN=e/KNN;
    float wv=w2[rbase+e];
    float nm=(MODE==0)?dis[b*n+sN]*wv*dd:wv;
    float4 r = RAW ? loadx4(xraw,fl,((size_t)b*n+sN)*HD+c4)
                   : *(const float4*)(Hb+(size_t)sN*HD+c4);
    a.x=fmaf(nm,r.x,a.x); a.y=fmaf(nm,r.y,a.y); a.z=fmaf(nm,r.z,a.z); a.w=fmaf(nm,r.w,a.w);
  }
  if (MODE==0){
    float4 xr=loadx4(xraw,fl,((size_t)b*NMAX+cum[b*NMAX+d])*HD+c4);
    a.x=0.8f*a.x+0.2f*xr.x; a.y=0.8f*a.y+0.2f*xr.y;
    a.z=0.8f*a.z+0.2f*xr.z; a.w=0.8f*a.w+0.2f*xr.w;
  }
  *(float4*)(outp+(size_t)wid*HD+c4)=a;
}

// ---------------- panel GEMM, 8x8 thread tile, full 256 cols (stage-0 workhorse) ----------------
__global__ void k_mm(const float* __restrict__ A1, const float* __restrict__ B1,
                     const float* __restrict__ A2, const float* __restrict__ B2,
                     const float* __restrict__ bias, int relu,
                     float* __restrict__ Cout, int M){
  __shared__ __align__(16) float As[16][68];
  __shared__ __align__(16) float Bs[16][260];
  int tid=threadIdx.x, bm=blockIdx.x;
  int tr=tid>>5, tc=tid&31;
  float acc[8][8];
  #pragma unroll
  for (int i=0;i<8;i++){
    #pragma unroll
    for (int j=0;j<8;j++) acc[i][j]=0.f;
  }
  int l=tid*4;
  int ar=l>>4, ak=l&15;
  int arow=bm*64+ar;
  int KT = A2 ? 512 : 256;
  for (int k0=0;k0<KT;k0+=16){
    const float* Asrc=(k0<HD)?A1:A2;
    const float* Bsrc=(k0<HD)?B1:B2;
    int kc=k0&(HD-1);
    if (arow<M){
      float4 a4=*(const float4*)(Asrc+(size_t)arow*HD+kc+ak);
      As[ak][ar]=a4.x; As[ak+1][ar]=a4.y; As[ak+2][ar]=a4.z; As[ak+3][ar]=a4.w;
    } else {
      As[ak][ar]=0.f; As[ak+1][ar]=0.f; As[ak+2][ar]=0.f; As[ak+3][ar]=0.f;
    }
    #pragma unroll
    for (int c=0;c<4;c++){
      int idx=c*256+tid;
      int rkk=idx>>6, cc=(idx&63)*4;
      *(float4*)&Bs[rkk][cc]=*(const float4*)(Bsrc+(size_t)(kc+rkk)*HD+cc);
    }
    __syncthreads();
    #pragma unroll
    for (int kk=0;kk<16;kk++){
      float af[8], bf[8];
      *(float4*)&af[0]=*(const float4*)&As[kk][tr*8];
      *(float4*)&af[4]=*(const float4*)&As[kk][tr*8+4];
      *(float4*)&bf[0]=*(const float4*)&Bs[kk][tc*8];
      *(float4*)&bf[4]=*(const float4*)&Bs[kk][tc*8+4];
      #pragma unroll
      for (int i=0;i<8;i++){
        #pragma unroll
        for (int j=0;j<8;j++) acc[i][j]=fmaf(af[i],bf[j],acc[i][j]);
      }
    }
    __syncthreads();
  }
  #pragma unroll
  for (int i=0;i<8;i++){
    int grow=bm*64+tr*8+i;
    if (grow>=M) continue;
    #pragma unroll
    for (int j=0;j<8;j++){
      int gcol=tc*8+j;
      float v=acc[i][j];
      if (bias) v+=bias[gcol];
      if (relu) v=fmaxf(v,0.f);
      Cout[(size_t)grow*HD+gcol]=v;
    }
  }
}

// ---------------- col-split GEMM (round-10-proven 4x4 inner, NCOLB=2):
// 64 rows x 128 cols per block, grid.y=2. OUT-OF-PLACE ONLY. For small stages.
__global__ void k_mm2(const float* __restrict__ A1, const float* __restrict__ B1,
                      const float* __restrict__ A2, const float* __restrict__ B2,
                      const float* __restrict__ bias, int relu,
                      float* __restrict__ Cout, int M){
  __shared__ __align__(16) float As[16][68];
  __shared__ __align__(16) float Bs[16][132];
  int tid=threadIdx.x, bm=blockIdx.x;
  int colbase=blockIdx.y*128;
  int tm=tid>>4, tn=tid&15;
  float acc[2][4][4];
  #pragma unroll
  for (int b2=0;b2<2;b2++){
    #pragma unroll
    for (int i=0;i<4;i++){
      #pragma unroll
      for (int j=0;j<4;j++) acc[b2][i][j]=0.f;
    }
  }
  int l=tid*4;
  int ar=l>>4, ak=l&15;
  int arow=bm*64+ar;
  int KT = A2 ? 512 : 256;
  for (int k0=0;k0<KT;k0+=16){
    const float* Asrc=(k0<HD)?A1:A2;
    const float* Bsrc=(k0<HD)?B1:B2;
    int kc=k0&(HD-1);
    if (arow<M){
      float4 a4=*(const float4*)(Asrc+(size_t)arow*HD+kc+ak);
      As[ak][ar]=a4.x; As[ak+1][ar]=a4.y; As[ak+2][ar]=a4.z; As[ak+3][ar]=a4.w;
    } else {
      As[ak][ar]=0.f; As[ak+1][ar]=0.f; As[ak+2][ar]=0.f; As[ak+3][ar]=0.f;
    }
    #pragma unroll
    for (int c=0;c<2;c++){
      int idx=c*256+tid;                 // 512 float4 slots = 16 rows x 32 col4
      int rkk=idx>>5, cc=(idx&31)*4;
      *(float4*)&Bs[rkk][cc]=*(const float4*)(Bsrc+(size_t)(kc+rkk)*HD+colbase+cc);
    }
    __syncthreads();
    #pragma unroll
    for (int kk=0;kk<16;kk++){
      float4 av=*(const float4*)&As[kk][tm*4];
      #pragma unroll
      for (int b2=0;b2<2;b2++){
        float4 bv=*(const float4*)&Bs[kk][b2*64+tn*4];
        acc[b2][0][0]=fmaf(av.x,bv.x,acc[b2][0][0]); acc[b2][0][1]=fmaf(av.x,bv.y,acc[b2][0][1]);
        acc[b2][0][2]=fmaf(av.x,bv.z,acc[b2][0][2]); acc[b2][0][3]=fmaf(av.x,bv.w,acc[b2][0][3]);
        acc[b2][1][0]=fmaf(av.y,bv.x,acc[b2][1][0]); acc[b2][1][1]=fmaf(av.y,bv.y,acc[b2][1][1]);
        acc[b2][1][2]=fmaf(av.y,bv.z,acc[b2][1][2]); acc[b2][1][3]=fmaf(av.y,bv.w,acc[b2][1][3]);
        acc[b2][2][0]=fmaf(av.z,bv.x,acc[b2][2][0]); acc[b2][2][1]=fmaf(av.z,bv.y,acc[b2][2][1]);
        acc[b2][2][2]=fmaf(av.z,bv.z,acc[b2][2][2]); acc[b2][2][3]=fmaf(av.z,bv.w,acc[b2][2][3]);
        acc[b2][3][0]=fmaf(av.w,bv.x,acc[b2][3][0]); acc[b2][3][1]=fmaf(av.w,bv.y,acc[b2][3][1]);
        acc[b2][3][2]=fmaf(av.w,bv.z,acc[b2][3][2]); acc[b2][3][3]=fmaf(av.w,bv.w,acc[b2][3][3]);
      }
    }
    __syncthreads();
  }
  #pragma unroll
  for (int i=0;i<4;i++){
    int grow=bm*64+tm*4+i;
    if (grow>=M) continue;
    #pragma unroll
    for (int b2=0;b2<2;b2++){
      #pragma unroll
      for (int j=0;j<4;j++){
        int gcol=colbase+b2*64+tn*4+j;
        float v=acc[b2][i][j];
        if (bias) v+=bias[gcol];
        if (relu) v=fmaxf(v,0.f);
        Cout[(size_t)grow*HD+gcol]=v;
      }
    }
  }
}

// ---------------- va = rowdot(Wlin, wa); va[256] = blin . wa ----------------
__global__ void k_va(const float* __restrict__ Wlin, const float* __restrict__ wa,
                     const float* __restrict__ blin, float* __restrict__ va){
  int i=threadIdx.x;
  float acc=0.f;
  for (int j=0;j<HD;j++) acc=fmaf(Wlin[(size_t)i*HD+j],wa[j],acc);
  va[i]=acc;
  if (i==0){
    float c=0.f;
    for (int j=0;j<HD;j++) c=fmaf(blin[j],wa[j],c);
    va[256]=c;
  }
}

// ---------------- fused: pb, qd (XCD-local) ----------------
__global__ void k_qd(const float* __restrict__ T, const float* __restrict__ wb,
                     const float* __restrict__ va, const int* __restrict__ nbr,
                     const int* __restrict__ rev, const int* __restrict__ offs,
                     const unsigned char* __restrict__ val2,
                     float* __restrict__ pb, float* __restrict__ qd, int n){
  int b,d;
  xcd_map(blockIdx.x,threadIdx.x>>6,n,b,d);
  int lane=threadIdx.x&63;
  if (d>=n) return;
  int wid=b*n+d;
  int c4=lane*4;
  float4 r1=*(const float4*)(T+(size_t)wid*HD+c4);
  float4 wb4=*(const float4*)(wb+c4);
  float p=r1.x*wb4.x+r1.y*wb4.y+r1.z*wb4.z+r1.w*wb4.w;
  const float* Tb=T+(size_t)b*n*HD;
  float4 m4=make_float4(-INFINITY,-INFINITY,-INFINITY,-INFINITY);
  #pragma unroll
  for (int k=0;k<KNN;k++){
    int sN=nbr[(size_t)wid*KNN+k];
    float4 r=*(const float4*)(Tb+(size_t)sN*HD+c4);
    m4.x=fmaxf(m4.x,r.x); m4.y=fmaxf(m4.y,r.y); m4.z=fmaxf(m4.z,r.z); m4.w=fmaxf(m4.w,r.w);
  }
  size_t rbase=(size_t)b*n*KNN;
  int lo=offs[b*(n+1)+d], hi=offs[b*(n+1)+d+1];
  for (int sl=lo;sl<hi;sl++){
    int e=rev[rbase+sl];
    if (!val2[rbase+e]) continue;
    int sN=e/KNN;
    float4 r=*(const float4*)(Tb+(size_t)sN*HD+c4);
    m4.x=fmaxf(m4.x,r.x); m4.y=fmaxf(m4.y,r.y); m4.z=fmaxf(m4.z,r.z); m4.w=fmaxf(m4.w,r.w);
  }
  float4 va4=*(const float4*)(va+c4);
  float q=va4.x*m4.x+va4.y*m4.y+va4.z*m4.z+va4.w*m4.w;
  #pragma unroll
  for (int o=32;o>0;o>>=1){ p+=__shfl_xor(p,o); q+=__shfl_xor(q,o); }
  if (lane==0){ pb[wid]=p; qd[wid]=q+va[256]; }
}

// ---------------- attention softmax + xn + fused LEConv dots (XCD-local) ----------------
__global__ void k_attxn(const float* __restrict__ Hin, const float* __restrict__ pb,
                        const float* __restrict__ qd, const int* __restrict__ nbr,
                        const int* __restrict__ rev, const int* __restrict__ offs,
                        const unsigned char* __restrict__ val2, const float* __restrict__ abatt,
                        const float* __restrict__ lW1, const float* __restrict__ lb1,
                        const float* __restrict__ lW2, const float* __restrict__ lW3,
                        const float* __restrict__ lb3,
                        float* __restrict__ av, float* __restrict__ bbv, float* __restrict__ l3v,
                        float* __restrict__ Tout, int n){
  int b,d;
  xcd_map(blockIdx.x,threadIdx.x>>6,n,b,d);
  int lane=threadIdx.x&63;
  if (d>=n) return;
  int wid=b*n+d;
  float batt=abatt[0];
  float qs=qd[wid];
  const float* Hb=Hin+(size_t)b*n*HD;
  int c4=lane*4;
  size_t rbase=(size_t)b*n*KNN;
  int lo=offs[b*(n+1)+d], hi=offs[b*(n+1)+d+1];
  float smax=-INFINITY;
  #pragma unroll
  for (int k=0;k<KNN;k++){
    int sN=nbr[(size_t)wid*KNN+k];
    float sc=qs+pb[b*n+sN]+batt;
    sc=sc>=0.f?sc:0.2f*sc;
    smax=fmaxf(smax,sc);
  }
  for (int sl=lo;sl<hi;sl++){
    int e=rev[rbase+sl];
    if (!val2[rbase+e]) continue;
    int sN=e/KNN;
    float sc=qs+pb[b*n+sN]+batt;
    sc=sc>=0.f?sc:0.2f*sc;
    smax=fmaxf(smax,sc);
  }
  float es=0.f;
  float4 a=make_float4(0.f,0.f,0.f,0.f);
  #pragma unroll
  for (int k=0;k<KNN;k++){
    int sN=nbr[(size_t)wid*KNN+k];
    float sc=qs+pb[b*n+sN]+batt;
    sc=sc>=0.f?sc:0.2f*sc;
    float e2=expf(sc-smax);
    es+=e2;
    float4 r=*(const float4*)(Hb+(size_t)sN*HD+c4);
    a.x=fmaf(e2,r.x,a.x); a.y=fmaf(e2,r.y,a.y); a.z=fmaf(e2,r.z,a.z); a.w=fmaf(e2,r.w,a.w);
  }
  for (int sl=lo;sl<hi;sl++){
    int e=rev[rbase+sl];
    if (!val2[rbase+e]) continue;
    int sN=e/KNN;
    float sc=qs+pb[b*n+sN]+batt;
    sc=sc>=0.f?sc:0.2f*sc;
    float e2=expf(sc-smax);
    es+=e2;
    float4 r=*(const float4*)(Hb+(size_t)sN*HD+c4);
    a.x=fmaf(e2,r.x,a.x); a.y=fmaf(e2,r.y,a.y); a.z=fmaf(e2,r.z,a.z); a.w=fmaf(e2,r.w,a.w);
  }
  float inv=1.f/es;
  a.x*=inv; a.y*=inv; a.z*=inv; a.w*=inv;
  *(float4*)(Tout+(size_t)wid*HD+c4)=a;
  float4 w1v=*(const float4*)(lW1+c4);
  float4 w2v=*(const float4*)(lW2+c4);
  float4 w3v=*(const float4*)(lW3+c4);
  float s1=a.x*w1v.x+a.y*w1v.y+a.z*w1v.z+a.w*w1v.w;
  float s2=a.x*w2v.x+a.y*w2v.y+a.z*w2v.z+a.w*w2v.w;
  float s3=a.x*w3v.x+a.y*w3v.y+a.z*w3v.z+a.w*w3v.w;
  #pragma unroll
  for (int o=32;o>0;o>>=1){ s1+=__shfl_xor(s1,o); s2+=__shfl_xor(s2,o); s3+=__shfl_xor(s3,o); }
  if (lane==0){ av[wid]=s1+lb1[0]; bbv[wid]=s2; l3v[wid]=s3+lb3[0]; }
}

__global__ void k_fit(const float* __restrict__ av, const float* __restrict__ bbv,
                      const float* __restrict__ l3v, const int* __restrict__ nbr,
                      const int* __restrict__ rev, const int* __restrict__ offs,
                      const unsigned char* __restrict__ val2, float* __restrict__ fit, int n){
  int t=blockIdx.x*256+threadIdx.x;
  if (t>=BB*n) return;
  int b=t/n, d=t-b*n;
  size_t rbase=(size_t)b*n*KNN;
  float ms=0.f; int cv=KNN;
  #pragma unroll
  for (int k=0;k<KNN;k++) ms+=av[b*n+nbr[(size_t)t*KNN+k]];
  int lo=offs[b*(n+1)+d], hi=offs[b*(n+1)+d+1];
  for (int sl=lo;sl<hi;sl++){
    int e=rev[rbase+sl];
    if (val2[rbase+e]){ ms+=av[b*n+e/KNN]; cv++; }
  }
  float z=ms-(float)cv*bbv[t]+l3v[t];
  fit[t]=1.f/(1.f+expf(-z));
}

// ---------------- top-k by rank-counting, LDS-staged ----------------
__global__ void k_rank(const float* __restrict__ fit, float* __restrict__ svl,
                       int* __restrict__ sid, int n, int kp){
  __shared__ float sf[2048];
  int b=blockIdx.y;
  int i=blockIdx.x*256+threadIdx.x;
  const float* fb=fit+(size_t)b*n;
  for (int j=threadIdx.x;j<n;j+=256) sf[j]=fb[j];
  __syncthreads();
  if (i>=n) return;
  float fi=sf[i];
  int rank=0;
  for (int j=0;j<n;j++){
    float fj=sf[j];
    if (fj>fi || (fj==fi && j<i)) rank++;
  }
  if (rank<kp){ svl[b*NMAX+rank]=fi; sid[b*NMAX+rank]=i; }
}

// ---------------- pool gather (float4) ----------------
__global__ void k_pool(const float* __restrict__ T, const float* __restrict__ svl,
                       const int* __restrict__ sid, const int* __restrict__ cumA,
                       int* __restrict__ cumB, float* __restrict__ Hout, int n, int kp){
  int wid=blockIdx.x*4+(threadIdx.x>>6);
  int lane=threadIdx.x&63;
  if (wid>=BB*kp) return;
  int b=wid/kp, j=wid-b*kp;
  int srcn=sid[b*NMAX+j];
  if (srcn<0) srcn=0;
  if (srcn>=n) srcn=n-1;
  float vv=svl[b*NMAX+j];
  int c4=lane*4;
  float4 r=*(const float4*)(T+((size_t)b*n+srcn)*HD+c4);
  r.x*=vv; r.y*=vv; r.z*=vv; r.w*=vv;
  *(float4*)(Hout+((size_t)b*kp+j)*HD+c4)=r;
  if (lane==0) cumB[b*NMAX+j]=cumA[b*NMAX+srcn];
}

// ---------------- readout: [mean | max], 4-wave parallel ----------------
__global__ void k_readout(const float* __restrict__ Hb, float* __restrict__ ro, int n){
  __shared__ float ss[4][256], sm[4][256];
  int b=blockIdx.x, tid=threadIdx.x;
  int wv=tid>>6, lane=tid&63;
  int c4=lane*4;
  float4 s=make_float4(0.f,0.f,0.f,0.f);
  float4 m=make_float4(-INFINITY,-INFINITY,-INFINITY,-INFINITY);
  for (int i=wv;i<n;i+=4){
    float4 v=*(const float4*)(Hb+((size_t)b*n+i)*HD+c4);
    s.x+=v.x; s.y+=v.y; s.z+=v.z; s.w+=v.w;
    m.x=fmaxf(m.x,v.x); m.y=fmaxf(m.y,v.y); m.z=fmaxf(m.z,v.z); m.w=fmaxf(m.w,v.w);
  }
  *(float4*)&ss[wv][c4]=s;
  *(float4*)&sm[wv][c4]=m;
  __syncthreads();
  int h=tid;
  float acc=ss[0][h]+ss[1][h]+ss[2][h]+ss[3][h];
  float mx=fmaxf(fmaxf(sm[0][h],sm[1][h]),fmaxf(sm[2][h],sm[3][h]));
  ro[b*512+h]=acc/(float)n;
  ro[b*512+256+h]=mx;
}

// ---------------- final ----------------
__global__ void k_final(const float* __restrict__ Hb, const float* __restrict__ gW,
                        const float* __restrict__ gb, const float* __restrict__ nW,
                        const float* __restrict__ nbias, const float* __restrict__ ro0,
                        const float* __restrict__ ro1, float* __restrict__ outp, int n){
  int b=blockIdx.x, tid=threadIdx.x;
  int wv=tid>>6, lane=tid&63;
  __shared__ float gate[64];
  for (int i=wv;i<n;i+=4){
    const float* r=Hb+((size_t)b*n+i)*HD;
    float p=0.f;
    for (int h=lane;h<HD;h+=64) p=fmaf(r[h],gW[h],p);
    #pragma unroll
    for (int o=32;o>0;o>>=1) p+=__shfl_xor(p,o);
    if (lane==0) gate[i]=p+gb[0];
  }
  __syncthreads();
  if (tid==0){
    float mx=-INFINITY;
    for (int i=0;i<n;i++) mx=fmaxf(mx,gate[i]);
    float sm=0.f;
    for (int i=0;i<n;i++){ gate[i]=expf(gate[i]-mx); sm+=gate[i]; }
    float inv=1.f/sm;
    for (int i=0;i<n;i++) gate[i]*=inv;
  }
  __syncthreads();
  if (tid<OUTD){
    float acc=0.f;
    for (int i=0;i<n;i++){
      const float* r=Hb+((size_t)b*n+i)*HD;
      float dot=0.f;
      for (int h=0;h<HD;h++) dot=fmaf(r[h],nW[(size_t)h*OUTD+tid],dot);
      acc=fmaf(gate[i],dot+nbias[tid],acc);
    }
    outp[(size_t)b*1152+tid]=acc;
  }
  for (int q=tid;q<512;q+=256){
    outp[(size_t)b*1152+128+q]=ro1[b*512+q];
    outp[(size_t)b*1152+640+q]=ro0[b*512+q];
  }
}

// =======================================================================
extern "C" void kernel_launch(void* const* d_in, const int* in_sizes, int n_in,
                              void* d_out, int out_size, void* d_ws, size_t ws_size,
                              hipStream_t stream){
  if (n_in<27) return;
  if (in_sizes[0]!=BB*NMAX*HD || in_sizes[1]!=BB*NMAX*3) return;
  float* outp=(float*)d_out;
  (void)out_size;

  char* p=(char*)d_ws;
  auto carve=[&](size_t bytes)->char*{ char* r=p; p+=((bytes+255)/256)*256; return r; };
  float* posF=(float*)carve((size_t)BB*NMAX*3*4);
  float* posf=(float*)carve((size_t)BB*NMAX*3*4);
  float* Hbuf=(float*)carve((size_t)BB*NMAX*HD*4);
  float* Tbuf=(float*)carve((size_t)BB*NMAX*HD*4);
  float* XP  =(float*)carve((size_t)BB*308*HD*4);   // small-stage x_pool (OOP)
  static const int wcnt[25]={262144,128,128,128,128,128,128,128,4,
                             196608,768,196608,196608,768,1536,3,
                             768,3,768,768,3,256,1,32768,128};
  int woff[25]; int wtot=0;
  for (int i=0;i<25;i++){ woff[i]=wtot; wtot+=(wcnt[i]+63)&~63; }
  float* wsW=(float*)carve((size_t)wtot*4);
  int*   nbr =(int*)  carve((size_t)BB*NMAX*KNN*4);
  int*   rev =(int*)  carve((size_t)BB*NMAX*KNN*4);
  float* w1  =(float*)carve((size_t)BB*NMAX*KNN*4);
  float* w2  =(float*)carve((size_t)BB*NMAX*KNN*4);
  unsigned char* val2=(unsigned char*)carve((size_t)BB*NMAX*KNN);
  int* cnt  =(int*)carve((size_t)BB*NMAX*4);
  int* offs =(int*)carve((size_t)BB*(NMAX+1)*4);
  int* cur  =(int*)carve((size_t)BB*NMAX*4);
  float* dis=(float*)carve((size_t)BB*NMAX*4);
  float* pb =(float*)carve((size_t)BB*NMAX*4);
  float* qd =(float*)carve((size_t)BB*NMAX*4);
  float* av =(float*)carve((size_t)BB*NMAX*4);
  float* bbv=(float*)carve((size_t)BB*NMAX*4);
  float* l3v=(float*)carve((size_t)BB*NMAX*4);
  float* fit=(float*)carve((size_t)BB*NMAX*4);
  float* svl=(float*)carve((size_t)BB*NMAX*4);
  int*   sid=(int*)  carve((size_t)BB*NMAX*4);
  int* cumA =(int*)carve((size_t)BB*NMAX*4);
  int* cumB =(int*)carve((size_t)BB*NMAX*4);
  int* flag =(int*)carve(256);
  float* va =(float*)carve(272*4);
  float* ro0=(float*)carve((size_t)BB*512*4);
  float* ro1=(float*)carve((size_t)BB*512*4);
  size_t need=(size_t)(p-(char*)d_ws);
  if (ws_size<need) return;

  double* dcand=(double*)Tbuf;
  int*    icand=(int*)((char*)Tbuf + (size_t)BB*NCH*NMAX*KNN*8);

  k_detect<<<1,256,0,stream>>>(d_in[0],flag);
  k_cvtpos<<<(BB*NMAX*3+255)/256,256,0,stream>>>(d_in[1],flag,posF);
  {
    WTab tab;
    int maxc=0;
    for (int i=0;i<25;i++){ tab.src[i]=d_in[2+i]; tab.cnt[i]=wcnt[i]; tab.dst[i]=woff[i]; if (wcnt[i]>maxc) maxc=wcnt[i]; }
    k_cvtw<<<dim3((maxc+255)/256,25),256,0,stream>>>(tab,flag,wsW);
  }
  k_initcum<<<(BB*NMAX+255)/256,256,0,stream>>>(cumA);

  const int NS[4]={2048,308,77,39};
  const int KP[3]={308,77,39};

  for (int s=0;s<4;s++){
    int n=NS[s]; int M=BB*n;
    int gG=BB*((n+3)/4);
    const float* wconv =wsW+woff[0]+(size_t)s*65536;
    const float* eW1p  =wsW+woff[1]+s*32;
    const float* eb1p  =wsW+woff[2]+s*32;
    const float* gp    =wsW+woff[3]+s*32;
    const float* bep   =wsW+woff[4]+s*32;
    const float* mp    =wsW+woff[5]+s*32;
    const float* vp    =wsW+woff[6]+s*32;
    const float* W2p   =wsW+woff[7]+s*32;
    const float* b2p   =wsW+woff[8]+s;
    const float* aWrelp=wsW+woff[9]+(size_t)s*65536;
    const float* abrelp=wsW+woff[10]+s*256;
    const float* aWrootp=wsW+woff[11]+(size_t)s*65536;
    const float* aWlinp=wsW+woff[12]+(size_t)s*65536;
    const float* ablinp=wsW+woff[13]+s*256;
    const float* wap   =wsW+woff[14]+s*512;
    const float* wbp   =wsW+woff[14]+s*512+256;
    const float* abattp=wsW+woff[15]+s;
    const float* leW1p =wsW+woff[16]+s*256;
    const float* leb1p =wsW+woff[17]+s;
    const float* leW2p =wsW+woff[18]+s*256;
    const float* leW3p =wsW+woff[19]+s*256;
    const float* leb3p =wsW+woff[20]+s;

    const float* pf;
    if (s==0){
      pf=posF;
    } else {
      k_gatherpos<<<(BB*n*3+255)/256,256,0,stream>>>(posF,cumA,posf,n);
      pf=posf;
    }
    k_knn_part<<<dim3((n+255)/256,NCH,BB),256,0,stream>>>(pf,dcand,icand,n);
    k_knn_merge<<<(BB*n+255)/256,256,0,stream>>>(dcand,icand,nbr,cnt,cur,n);
    int totE=BB*n*KNN;
    k_edge<<<(totE+255)/256,256,0,stream>>>(pf,nbr,w1,w2,val2,cnt,
        eW1p,eb1p,gp,bep,mp,vp,W2p,b2p,n);
    k_csr_scan<<<BB,256,0,stream>>>(cnt,offs,n);
    k_csr_fill<<<(totE+255)/256,256,0,stream>>>(nbr,offs,cur,rev,n);
    k_sortdeg<<<(BB*n+255)/256,256,0,stream>>>(rev,offs,w1,w2,dis,n);
    if (s==1) k_readout<<<BB,256,0,stream>>>(Hbuf,ro0,n);
    if (s==2) k_readout<<<BB,256,0,stream>>>(Hbuf,ro1,n);
    if (s==0)
      k_nbrsum<0,1><<<gG,256,0,stream>>>(nullptr,w1,w2,nbr,rev,offs,dis,d_in[0],flag,cumA,Tbuf,n);
    else
      k_nbrsum<0,0><<<gG,256,0,stream>>>(Hbuf,w1,w2,nbr,rev,offs,dis,d_in[0],flag,cumA,Tbuf,n);
    if (s==0)
      k_mm<<<(M+63)/64,256,0,stream>>>(Tbuf,wconv,(const float*)nullptr,(const float*)nullptr,
                                       (const float*)nullptr,1,Hbuf,M);
    else
      k_mm2<<<dim3((M+63)/64,2),256,0,stream>>>(Tbuf,wconv,(const float*)nullptr,(const float*)nullptr,
                                                (const float*)nullptr,1,Hbuf,M);
    if (s<3){
      int kp=KP[s];
      k_nbrsum<1,0><<<gG,256,0,stream>>>(Hbuf,w1,w2,nbr,rev,offs,dis,d_in[0],flag,cumA,Tbuf,n);
      const float* xp;
      if (s==0){
        // in-place, full-width (proven)
        k_mm<<<(M+63)/64,256,0,stream>>>(Tbuf,aWrelp,Hbuf,aWrootp,abrelp,0,Tbuf,M);
        xp=Tbuf;
      } else {
        // out-of-place into XP, col-split for latency
        k_mm2<<<dim3((M+63)/64,2),256,0,stream>>>(Tbuf,aWrelp,Hbuf,aWrootp,abrelp,0,XP,M);
        xp=XP;
      }
      k_va<<<1,256,0,stream>>>(aWlinp,wap,ablinp,va);
      k_qd<<<gG,256,0,stream>>>(xp,wbp,va,nbr,rev,offs,val2,pb,qd,n);
      k_attxn<<<gG,256,0,stream>>>(Hbuf,pb,qd,nbr,rev,offs,val2,abattp,
                                   leW1p,leb1p,leW2p,leW3p,leb3p,av,bbv,l3v,Tbuf,n);
      k_fit<<<(BB*n+255)/256,256,0,stream>>>(av,bbv,l3v,nbr,rev,offs,val2,fit,n);
      k_rank<<<dim3((n+255)/256,BB),256,0,stream>>>(fit,svl,sid,n,kp);
      k_pool<<<(BB*kp+3)/4,256,0,stream>>>(Tbuf,svl,sid,cumA,cumB,Hbuf,n,kp);
      { int* t=cumA; cumA=cumB; cumB=t; }
    }
  }
  k_final<<<BB,256,0,stream>>>(Hbuf,wsW+woff[21],wsW+woff[22],wsW+woff[23],wsW+woff[24],
                               ro0,ro1,outp,NS[3]);
}